// Round 6
// baseline (591.239 us; speedup 1.0000x reference)
//
#include <hip/hip_runtime.h>
#include <math.h>

typedef unsigned short u16;
typedef unsigned int u32;
typedef __bf16 bf16x8 __attribute__((ext_vector_type(8)));
typedef float f32x4 __attribute__((ext_vector_type(4)));

__device__ __forceinline__ u16 f2b(float f) {
    u32 u = __float_as_uint(f);
    return (u16)((u + 0x7FFFu + ((u >> 16) & 1u)) >> 16);
}
__device__ __forceinline__ float b2f(u16 h) {
    return __uint_as_float(((u32)h) << 16);
}

// async global->LDS, 16B per lane. LDS dest is wave-uniform base + lane*16.
#define GLL16(gp, lp)                                                          \
    __builtin_amdgcn_global_load_lds(                                          \
        (__attribute__((address_space(1))) void*)(const_cast<u16*>(gp)),       \
        (__attribute__((address_space(3))) void*)(lp), 16, 0, 0)

// ---------------------------------------------------------------------------
// 256x256 NT GEMM — m201-faithful fine-phase schedule. 8 waves (2M x 4N),
// BK=64, LDS 128 KiB (2 dbuf x (A 32K + B 32K)).
//
// Per K-tile: 4 quadrant phases q=(rq=q>>1, cq=q&1), 16 MFMA each
// (4 i-frags x 2 j-frags x 2 k-halves). Register caching: A frags live
// across the cq-pair (refreshed at q0,q2), B frags live across the rq-pair
// (refreshed at q0: cq0, q1: cq1). Reads/phase: 12 / 4 / 8 / 0.
//
// Phase body (m196/m201: the fine ds_read∥GLL∥MFMA interleave is the lever;
// MFMA window between two barriers is pure-MFMA so the LDS pipe serves the
// next phase's read-bursts while the matrix pipe drains):
//   reads ; 2 GLL ; [q0: lgkmcnt(8) hint] ; s_barrier ;
//   lgkmcnt(0)+sched_barrier (rule #18) ; setprio(1) 16 MFMA setprio(0) ;
//   [q1: vmcnt | q3: vmcnt] ; s_barrier
//
// Counted-vmcnt ledger (r3-audited, never 0 mid-loop). GLL slots for tile
// T+1 into buf^1: q0: B0,B1 | q1: B2,B3 | q2: A0,A2 | q3: A1,A3.
//   steady entry: outstanding = T's A1,A3 (2).
//   q1-end vmcnt(4): retire T's A1,A3 (needed by q2's rq=1 reads);
//                    T+1's B0..B3 stay (4).
//   q3-end vmcnt(2): retire T+1's B*,A0,A2 (needed by next q0/q1);
//                    T+1's A1,A3 stay in flight.
//   tails: last tile q1-end vmcnt(0), no q3 wait.
//   prologue: tile0's 8 lines (B0..B3,A0,A2,A1,A3) -> vmcnt(2).
//
// LDS swizzle (T2): logical k-chunk kc stored at physical chunk
// kc ^ ((row>>1)&7) via inverse-swizzled GLOBAL source (GLL dest stays
// linear, rule #21); fragment ds_read applies the same XOR. 0 conflicts
// (verified rounds 1-5: 2 lanes/16B-slot = free 2-way).
//
// MODE 0: 2-D row x col grid, XCD-swizzled by row tile (QKV / proj), bz=0.
// MODE 1: batch x tril-tile grid (wei): bz=n&15, t=n>>4 in 0..9 lower-tri.
// MODE 2: batch x full 4x4 grid (attn): kEnd=(by+1)*256 causal truncation.
// EPI  0: +bias, pair-rotate -> bf16 (k/q/vT split; v stored transposed)
//      1: softplus(scale*x) causal-masked -> bf16
//      2: inverse pair-rotate -> bf16
//      3: +bias -> f32
// ---------------------------------------------------------------------------
template <int EPI, int MODE>
__global__ __launch_bounds__(512, 2) void gemm256(
    const u16* __restrict__ A, long long sAz,
    const u16* __restrict__ B, long long sBz,
    void* __restrict__ D0, void* __restrict__ D1, void* __restrict__ D2,
    long long sDz,
    const float* __restrict__ bias0, const float* __restrict__ bias1,
    const float* __restrict__ bias2,
    const u32* __restrict__ cossin,
    int N, int K, float scale, int WB)
{
    extern __shared__ u16 lds[];
    u16* const As = lds;                    // [2][4 chunks][64 rows][64]
    u16* const Bs = lds + 2 * 256 * 64;

    int bx, by, bz;
    if (MODE == 0) {
        const int n = blockIdx.x;
        const int xcd = n & 7, m = n >> 3;
        by = xcd + 8 * (m / WB);
        bx = m % WB;
        bz = 0;
    } else if (MODE == 1) {
        const int n = blockIdx.x;
        bz = n & 15;
        const int t = n >> 4;               // 0..9 lower-triangular tile
        by = (t >= 1) + (t >= 3) + (t >= 6);
        bx = t - ((by * (by + 1)) >> 1);
    } else {
        const int n = blockIdx.x;
        bz = n & 15;
        const int t = n >> 4;               // 0..15
        by = t >> 2;
        bx = t & 3;
    }
    const int r0 = by * 256, c0 = bx * 256;

    const int kEnd = (MODE == 2) ? (((by + 1) * 256) < K ? ((by + 1) * 256) : K) : K;
    const int nkt = kEnd >> 6;

    const int tid = threadIdx.x;
    const int lane = tid & 63, wave = tid >> 6;
    const int wr = wave >> 2, wc = wave & 3;

    const u16* __restrict__ Ab = A + (long long)bz * sAz + (long long)r0 * K;
    const u16* __restrict__ Bb = B + (long long)bz * sBz + (long long)c0 * K;

    // staging: thread t fills LDS linearly (row = chunk*64 + tid/8, k-chunk =
    // tid&7); global source k-chunk pre-swizzled (inverse of the read XOR).
    const int srow = tid >> 3;
    const int skc8 = (((tid & 7) ^ ((tid >> 4) & 7))) * 8;

    // fragment-read constants (read XOR = (lane>>1)&7, matches stage inverse)
    const int lr = lane & 15;
    const int xr = (lane >> 1) & 7;
    const int kof0 = (((lane >> 4) + 0) ^ xr) * 8;   // k-half 0
    const int kof1 = (((lane >> 4) + 4) ^ xr) * 8;   // k-half 1

    f32x4 acc[8][4];
    #pragma unroll
    for (int i = 0; i < 8; ++i)
        #pragma unroll
        for (int j = 0; j < 4; ++j)
            acc[i][j] = (f32x4){0.f, 0.f, 0.f, 0.f};

    // prologue: tile0's 8 lines, A1,A3 last; leave A1,A3 in flight
    #pragma unroll
    for (int r = 0; r < 4; ++r)
        GLL16(Bb + (long long)(r * 64 + srow) * K + skc8, Bs + r * 4096 + tid * 8);
    GLL16(Ab + (long long)(0 * 64 + srow) * K + skc8, As + 0 * 4096 + tid * 8);
    GLL16(Ab + (long long)(2 * 64 + srow) * K + skc8, As + 2 * 4096 + tid * 8);
    GLL16(Ab + (long long)(1 * 64 + srow) * K + skc8, As + 1 * 4096 + tid * 8);
    GLL16(Ab + (long long)(3 * 64 + srow) * K + skc8, As + 3 * 4096 + tid * 8);
    asm volatile("s_waitcnt vmcnt(2)" ::: "memory");
    __builtin_amdgcn_s_barrier();

    for (int kt = 0; kt < nkt; ++kt) {
        const int buf = kt & 1;
        const u16* asb = As + buf * 16384;
        const u16* bsb = Bs + buf * 16384;
        u16* asn = As + (buf ^ 1) * 16384;
        u16* bsn = Bs + (buf ^ 1) * 16384;
        const long long kbn = (long long)(kt + 1) * 64 + skc8;
        const bool pf = (kt + 1 < nkt);
        bf16x8 a0[4], a1[4];                 // A frags, live across cq-pair
        bf16x8 b0[2][2], b1[2][2];           // B frags [cq][j], live across rq
        #pragma unroll
        for (int q = 0; q < 4; ++q) {
            const int rq = q >> 1, cq = q & 1;
            // ---- register refresh (12 / 4 / 8 / 0 ds_read_b128) ----
            if (cq == 0) {
                const int ab0 = wr * 128 + rq * 64;
                #pragma unroll
                for (int i = 0; i < 4; ++i) {
                    const int row = (ab0 + i * 16 + lr) * 64;
                    a0[i] = *(const bf16x8*)&asb[row + kof0];
                    a1[i] = *(const bf16x8*)&asb[row + kof1];
                }
            }
            if (q < 2) {
                const int bb0r = wc * 64 + q * 32;
                #pragma unroll
                for (int j = 0; j < 2; ++j) {
                    const int row = (bb0r + j * 16 + lr) * 64;
                    b0[q][j] = *(const bf16x8*)&bsb[row + kof0];
                    b1[q][j] = *(const bf16x8*)&bsb[row + kof1];
                }
            }
            // ---- stage slots: 2 GLL per phase for tile kt+1 ----
            if (pf) {
                if (q == 0) {
                    GLL16(Bb + (long long)(0 * 64 + srow) * K + kbn, bsn + 0 * 4096 + tid * 8);
                    GLL16(Bb + (long long)(1 * 64 + srow) * K + kbn, bsn + 1 * 4096 + tid * 8);
                } else if (q == 1) {
                    GLL16(Bb + (long long)(2 * 64 + srow) * K + kbn, bsn + 2 * 4096 + tid * 8);
                    GLL16(Bb + (long long)(3 * 64 + srow) * K + kbn, bsn + 3 * 4096 + tid * 8);
                } else if (q == 2) {
                    GLL16(Ab + (long long)(0 * 64 + srow) * K + kbn, asn + 0 * 4096 + tid * 8);
                    GLL16(Ab + (long long)(2 * 64 + srow) * K + kbn, asn + 2 * 4096 + tid * 8);
                } else {
                    GLL16(Ab + (long long)(1 * 64 + srow) * K + kbn, asn + 1 * 4096 + tid * 8);
                    GLL16(Ab + (long long)(3 * 64 + srow) * K + kbn, asn + 3 * 4096 + tid * 8);
                }
            }
            if (q == 0)
                asm volatile("s_waitcnt lgkmcnt(8)" ::: "memory");  // early hint
            __builtin_amdgcn_s_barrier();
            asm volatile("s_waitcnt lgkmcnt(0)" ::: "memory");
            __builtin_amdgcn_sched_barrier(0);   // rule #18: pin MFMA after wait
            __builtin_amdgcn_s_setprio(1);
            #pragma unroll
            for (int i = 0; i < 4; ++i)
                #pragma unroll
                for (int j = 0; j < 2; ++j) {
                    acc[rq * 4 + i][cq * 2 + j] = __builtin_amdgcn_mfma_f32_16x16x32_bf16(
                        a0[i], b0[cq][j], acc[rq * 4 + i][cq * 2 + j], 0, 0, 0);
                    acc[rq * 4 + i][cq * 2 + j] = __builtin_amdgcn_mfma_f32_16x16x32_bf16(
                        a1[i], b1[cq][j], acc[rq * 4 + i][cq * 2 + j], 0, 0, 0);
                }
            __builtin_amdgcn_s_setprio(0);
            if (q == 1) {
                // q2 reads this tile's A1,A3 (issued at prev tile's q3)
                if (pf) asm volatile("s_waitcnt vmcnt(4)" ::: "memory");
                else    asm volatile("s_waitcnt vmcnt(0)" ::: "memory");
            } else if (q == 3 && pf) {
                // next q0/q1 read kt+1's B*,A0,A2; A1,A3 stay in flight
                asm volatile("s_waitcnt vmcnt(2)" ::: "memory");
            }
            __builtin_amdgcn_s_barrier();
        }
    }

    // output routing (uniform per block)
    void* Dp = D0;
    const float* bp_ = bias0;
    int ldD = N, cbase = c0, sel = 0;
    if (EPI == 0) {
        sel = bx >> 2;                 // 4 tiles of 256 per 1024-col group
        Dp  = (sel == 0) ? D0 : (sel == 1) ? D1 : D2;
        bp_ = (sel == 0) ? bias0 : (sel == 1) ? bias1 : bias2;
        ldD = 1024;
        cbase = c0 & 1023;
    }

    // epilogue: C/D layout col=lane&15, row=(lane>>4)*4+reg
    const int rl = (lane >> 4) * 4, cl = lane & 15;
    const int grb = r0 + wr * 128;
    const int gcb = cbase + wc * 64;

    if (EPI == 0 && sel == 2) {
        // v group: bias + rotate + TRANSPOSED store into vT[b][c][t]
        #pragma unroll
        for (int ai = 0; ai < 8; ++ai) {
            #pragma unroll
            for (int bj = 0; bj < 4; ++bj) {
                const int gr0 = grb + ai * 16 + rl;       // 4-aligned t base
                const int gcd = gcb + bj * 16 + cl;       // v column
                u16 pk[4];
                #pragma unroll
                for (int v = 0; v < 4; ++v) {
                    const int gr = gr0 + v;
                    float my = acc[ai][bj][v] + bp_[gcd];
                    float other = __shfl_xor(my, 1);
                    u32 csn = cossin[(long long)gr * 512 + (gcd >> 1)];
                    float cs = b2f((u16)(csn & 0xffff)), sn = b2f((u16)(csn >> 16));
                    float res = (gcd & 1) ? (sn * other + cs * my)
                                          : (cs * my - sn * other);
                    pk[v] = f2b(res);
                }
                const int bb = gr0 >> 10, tt = gr0 & 1023;
                u16* dst = (u16*)Dp + ((((long long)bb << 10) + gcd) << 10) + tt;
                uint2 pw;
                pw.x = (u32)pk[0] | ((u32)pk[1] << 16);
                pw.y = (u32)pk[2] | ((u32)pk[3] << 16);
                *(uint2*)dst = pw;
            }
        }
        return;
    }

    #pragma unroll
    for (int ai = 0; ai < 8; ++ai) {
        #pragma unroll
        for (int bj = 0; bj < 4; ++bj) {
            const int gr0 = grb + ai * 16 + rl;
            const int gcd = gcb + bj * 16 + cl;
            #pragma unroll
            for (int v = 0; v < 4; ++v) {
                const int gr = gr0 + v;
                float val = acc[ai][bj][v];
                const long long o = (long long)bz * sDz + (long long)gr * ldD + gcd;
                if (EPI == 0) {
                    float my = val + bp_[gcd];
                    float other = __shfl_xor(my, 1);
                    u32 csn = cossin[(long long)gr * 512 + (gcd >> 1)];
                    float cs = b2f((u16)(csn & 0xffff)), sn = b2f((u16)(csn >> 16));
                    float res = (gcd & 1) ? (sn * other + cs * my)
                                          : (cs * my - sn * other);
                    ((u16*)Dp)[o] = f2b(res);
                } else if (EPI == 1) {
                    float xs = val * scale;
                    float r = (gcd <= gr) ? ((xs > 15.f) ? xs : log1pf(__expf(xs))) : 0.f;
                    ((u16*)Dp)[o] = f2b(r);
                } else if (EPI == 2) {
                    float my = val;
                    float other = __shfl_xor(my, 1);
                    u32 csn = cossin[((long long)((bz << 10) + gr)) * 512 + (gcd >> 1)];
                    float cs = b2f((u16)(csn & 0xffff)), sn = b2f((u16)(csn >> 16));
                    float res = (gcd & 1) ? (cs * my - sn * other)
                                          : (cs * my + sn * other);
                    ((u16*)Dp)[o] = f2b(res);
                } else {
                    ((float*)Dp)[o] = val + bp_[gcd];
                }
            }
        }
    }
}

// ---------------------------------------------------------------------------
// fp32 -> bf16 conversion, vectorized x4
// ---------------------------------------------------------------------------
__global__ void f2b_kern(const float* __restrict__ in, u16* __restrict__ out, int n4) {
    int i = blockIdx.x * blockDim.x + threadIdx.x;
    if (i >= n4) return;
    float4 f = ((const float4*)in)[i];
    uint2 o;
    o.x = (u32)f2b(f.x) | ((u32)f2b(f.y) << 16);
    o.y = (u32)f2b(f.z) | ((u32)f2b(f.w) << 16);
    ((uint2*)out)[i] = o;
}

// 4 weight matrices in one launch (blockIdx.y selects)
__global__ void f2b_w4(const float* __restrict__ a, const float* __restrict__ b,
                       const float* __restrict__ c, const float* __restrict__ d,
                       u16* __restrict__ oa, u16* __restrict__ ob,
                       u16* __restrict__ oc, u16* __restrict__ od, int n4) {
    int i = blockIdx.x * blockDim.x + threadIdx.x;
    if (i >= n4) return;
    const float* src = (blockIdx.y == 0) ? a : (blockIdx.y == 1) ? b
                     : (blockIdx.y == 2) ? c : d;
    u16* dst = (blockIdx.y == 0) ? oa : (blockIdx.y == 1) ? ob
             : (blockIdx.y == 2) ? oc : od;
    float4 f = ((const float4*)src)[i];
    uint2 o;
    o.x = (u32)f2b(f.x) | ((u32)f2b(f.y) << 16);
    o.y = (u32)f2b(f.z) | ((u32)f2b(f.w) << 16);
    ((uint2*)dst)[i] = o;
}

// ---------------------------------------------------------------------------
// Angle suffix-sum (angle[t] = sum_{s>=t} emb[idx[s]]) in 2 phases; phase 2
// computes its own chunk-suffix (no serial scan dispatch) and emits packed
// bf16 {cos, sin}.
// ---------------------------------------------------------------------------
#define TT 1024
#define CC2 512
#define NCH 32
#define CL 32

__global__ void angle_partial(const int* __restrict__ idx, const float* __restrict__ emb,
                              float* __restrict__ partial) {
    int b = blockIdx.x >> 5, ch = blockIdx.x & 31;
    int c = threadIdx.x;               // 0..511
    float s = 0.f;
    int tb = ch * CL;
    for (int t = 0; t < CL; t++) {
        int row = idx[b * TT + tb + t];
        s += emb[(long long)row * CC2 + c];
    }
    partial[((long long)b * NCH + ch) * CC2 + c] = s;
}

__global__ void angle_final(const int* __restrict__ idx, const float* __restrict__ emb,
                            const float* __restrict__ partial,
                            u32* __restrict__ cossin) {
    int b = blockIdx.x >> 5, ch = blockIdx.x & 31;
    int c = threadIdx.x;
    // exclusive suffix over chunks after ch (same accumulation order as the
    // old serial scan: descending cc)
    float run = 0.f;
    for (int cc = NCH - 1; cc > ch; cc--)
        run += partial[((long long)b * NCH + cc) * CC2 + c];
    for (int t = CL - 1; t >= 0; t--) {
        int tt = ch * CL + t;
        int row = idx[b * TT + tt];
        run += emb[(long long)row * CC2 + c];
        float sn, cs;
        __sincosf(run, &sn, &cs);
        cossin[((long long)b * TT + tt) * CC2 + c] = (u32)f2b(cs) | ((u32)f2b(sn) << 16);
    }
}

// ---------------------------------------------------------------------------
extern "C" void kernel_launch(void* const* d_in, const int* in_sizes, int n_in,
                              void* d_out, int out_size, void* d_ws, size_t ws_size,
                              hipStream_t stream) {
    const int Bn = 16, T = 1024, C = 1024;
    const long long TC = (long long)T * C;
    const size_t nx = (size_t)Bn * T * C;          // 16,777,216
    const size_t npairs = nx / 2;                  // 8,388,608

    const float* x   = (const float*)d_in[0];
    const int*   idx = (const int*)d_in[1];
    const float* Wk  = (const float*)d_in[2];
    const float* bk  = (const float*)d_in[3];
    const float* Wq  = (const float*)d_in[4];
    const float* bq  = (const float*)d_in[5];
    const float* Wv  = (const float*)d_in[6];
    const float* bv  = (const float*)d_in[7];
    const float* Wp  = (const float*)d_in[8];
    const float* bp  = (const float*)d_in[9];
    const float* emb = (const float*)d_in[10];
    float* out = (float*)d_out;

    // one-time: allow 128 KiB dynamic LDS on the 256^2 kernels
    static bool s_attr = false;
    if (!s_attr) {
        auto* k0 = gemm256<0, 0>;
        auto* k1 = gemm256<1, 1>;
        auto* k2 = gemm256<2, 2>;
        auto* k3 = gemm256<3, 0>;
        (void)hipFuncSetAttribute(reinterpret_cast<const void*>(k0),
                                  hipFuncAttributeMaxDynamicSharedMemorySize, 131072);
        (void)hipFuncSetAttribute(reinterpret_cast<const void*>(k1),
                                  hipFuncAttributeMaxDynamicSharedMemorySize, 131072);
        (void)hipFuncSetAttribute(reinterpret_cast<const void*>(k2),
                                  hipFuncAttributeMaxDynamicSharedMemorySize, 131072);
        (void)hipFuncSetAttribute(reinterpret_cast<const void*>(k3),
                                  hipFuncAttributeMaxDynamicSharedMemorySize, 131072);
        s_attr = true;
    }

    // workspace (~171 MB)
    u16* xb  = (u16*)d_ws;          // x bf16; aliased as wei after QKV
    u16* kb  = xb + nx;             // k (rotated by QKV epilogue)
    u16* qb  = kb + nx;             // q (rotated); y after attn GEMM
    u16* vT  = qb + nx;             // v rotated+transposed [B][C][T]
    u32* cossin = (u32*)(vT + nx);  // [B][T][512] packed bf16 {cos,sin}
    u16* Wall = (u16*)(cossin + npairs);           // [3072][1024] = Wk|Wq|Wv
    u16* Wpb  = Wall + (size_t)3 * C * C;
    float* partial = (float*)(Wpb + (size_t)C * C);  // [B][32][512]
    u16* wei = xb;                  // alias (x dead after QKV)

    // 1) conversions to bf16
    f2b_kern<<<(int)(nx / 4 / 256), 256, 0, stream>>>(x, xb, (int)(nx / 4));
    f2b_w4<<<dim3(C * C / 4 / 256, 4), 256, 0, stream>>>(
        Wk, Wq, Wv, Wp, Wall, Wall + (size_t)C * C, Wall + (size_t)2 * C * C, Wpb,
        C * C / 4);

    // 2) angle suffix-sum -> packed cos/sin (2 dispatches; suffix computed
    //    in-kernel, serial scan dispatch removed)
    angle_partial<<<Bn * NCH, 512, 0, stream>>>(idx, emb, partial);
    angle_final<<<Bn * NCH, 512, 0, stream>>>(idx, emb, partial, cossin);

    // 3) fused QKV projection: M=16384, N=3072, K=1024; 64x12 tiles.
    gemm256<0, 0><<<768, 512, 131072, stream>>>(
        xb, 0, Wall, 0, kb, qb, vT, 0, bk, bq, bv, cossin,
        3 * C, C, 1.f, 12);

    // 4) wei = softplus(k @ q^T / 32), causal: 16 batches x 10 tril tiles
    gemm256<1, 1><<<160, 512, 131072, stream>>>(
        kb, TC, qb, TC, wei, nullptr, nullptr, (long long)T * T,
        nullptr, nullptr, nullptr, nullptr, T, C, 0.03125f, 0);

    // 5) attn = wei @ v, inverse-rotation epilogue -> y (qb);
    //    16 batches x 16 tiles, K truncated at (by+1)*256 (causal)
    gemm256<2, 2><<<256, 512, 131072, stream>>>(
        wei, (long long)T * T, vT, (long long)C * T, qb, nullptr, nullptr, TC,
        nullptr, nullptr, nullptr, cossin, C, T, 1.f, 0);

    // 6) final projection -> f32 out: 64x4 tiles.
    gemm256<3, 0><<<256, 512, 131072, stream>>>(
        qb, 0, Wpb, 0, out, nullptr, nullptr, 0, bp, nullptr, nullptr, nullptr,
        C, C, 1.f, 4);
}

// Round 7
// 583.127 us; speedup vs baseline: 1.0139x; 1.0139x over previous
//
#include <hip/hip_runtime.h>
#include <math.h>

typedef unsigned short u16;
typedef unsigned int u32;
typedef __bf16 bf16x8 __attribute__((ext_vector_type(8)));
typedef float f32x4 __attribute__((ext_vector_type(4)));

__device__ __forceinline__ u16 f2b(float f) {
    u32 u = __float_as_uint(f);
    return (u16)((u + 0x7FFFu + ((u >> 16) & 1u)) >> 16);
}
__device__ __forceinline__ float b2f(u16 h) {
    return __uint_as_float(((u32)h) << 16);
}

// async global->LDS, 16B per lane. LDS dest is wave-uniform base + lane*16.
#define GLL16(gp, lp)                                                          \
    __builtin_amdgcn_global_load_lds(                                          \
        (__attribute__((address_space(1))) void*)(const_cast<u16*>(gp)),       \
        (__attribute__((address_space(3))) void*)(lp), 16, 0, 0)

// ---------------------------------------------------------------------------
// 256x256 NT GEMM, TWO phases per K-tile (32-MFMA clusters), one barrier per
// phase. 8 waves (2M x 4N), BK=64, LDS 128 KiB (2 dbuf x (A 32K + B 32K)).
//
// Phase p = rq (acc row-quadrant). rq=0: read 8 A-frags (chunk 2wr) + 8
// B-frags (both k-halves, reg-cached); rq=1: read 8 A-frags (chunk 2wr+1),
// reuse cached B.
//
// v7 (from r6 post-mortem): NO pre-MFMA lgkmcnt(0)/sched_barrier pin. At 1
// block/CU, 2 waves/SIMD, a full pre-MFMA drain serializes the LDS-read pipe
// against the matrix pipe (r5/r6 measured ~6300 cyc/K-tile vs ~3300 floor).
// Leaving the reads as compiler-visible loads lets hipcc emit fine-grained
// counted lgkmcnt between ds_read and MFMA (m97 mechanism) so each wave
// self-overlaps read-burst and MFMA-burst. The phase-end wait becomes
// `s_waitcnt vmcnt(N) lgkmcnt(0)` just before s_barrier: lgkm drain is free
// there (reads already consumed), and the "memory"-clobber asm before every
// barrier preserves the publish discipline (no memory op crosses a barrier).
//
// Counted-vmcnt ledger (T4, FIFO-audited, unchanged from r5). Issue slots:
//   ph0: next-tile A0,A2,B0,B1   ph1: next-tile B2,B3,A1,A3
// Waits:
//   ph0-end vmcnt(4): retire this tile's A1,A3 (issued prev ph1) for ph1.
//   ph1-end vmcnt(2): retire next-tile A0,A2,B0..B3; next A1,A3 in flight.
// Never drains to 0 mid-loop. Tails: last tile ph0-end vmcnt(0), no ph1 wait.
// Prologue: tile0's 8 issued with A1,A3 last -> vmcnt(2).
//
// LDS swizzle (T2): logical k-chunk kc stored at physical chunk
// kc ^ ((row>>1)&7) via inverse-swizzled GLOBAL source (GLL dest stays
// linear, rule #21); fragment ds_read applies the same XOR. 0 conflicts
// (verified rounds 1-6).
//
// MODE 0: 2-D row x col grid, XCD-swizzled by row tile (QKV / proj), bz=0.
// MODE 1: batch x tril-tile grid (wei): bz=n&15, t=n>>4 in 0..9 lower-tri.
// MODE 2: batch x full 4x4 grid (attn): kEnd=(by+1)*256 causal truncation.
// EPI  0: +bias, pair-rotate -> bf16 (k/q/vT split; v stored transposed)
//      1: softplus(scale*x) causal-masked -> bf16
//      2: inverse pair-rotate -> bf16
//      3: +bias -> f32
// ---------------------------------------------------------------------------
template <int EPI, int MODE>
__global__ __launch_bounds__(512, 2) void gemm256(
    const u16* __restrict__ A, long long sAz,
    const u16* __restrict__ B, long long sBz,
    void* __restrict__ D0, void* __restrict__ D1, void* __restrict__ D2,
    long long sDz,
    const float* __restrict__ bias0, const float* __restrict__ bias1,
    const float* __restrict__ bias2,
    const u32* __restrict__ cossin,
    int N, int K, float scale, int WB)
{
    extern __shared__ u16 lds[];
    u16* const As = lds;                    // [2][4 chunks][64 rows][64]
    u16* const Bs = lds + 2 * 256 * 64;

    int bx, by, bz;
    if (MODE == 0) {
        const int n = blockIdx.x;
        const int xcd = n & 7, m = n >> 3;
        by = xcd + 8 * (m / WB);
        bx = m % WB;
        bz = 0;
    } else if (MODE == 1) {
        const int n = blockIdx.x;
        bz = n & 15;
        const int t = n >> 4;               // 0..9 lower-triangular tile
        by = (t >= 1) + (t >= 3) + (t >= 6);
        bx = t - ((by * (by + 1)) >> 1);
    } else {
        const int n = blockIdx.x;
        bz = n & 15;
        const int t = n >> 4;               // 0..15
        by = t >> 2;
        bx = t & 3;
    }
    const int r0 = by * 256, c0 = bx * 256;

    const int kEnd = (MODE == 2) ? (((by + 1) * 256) < K ? ((by + 1) * 256) : K) : K;
    const int nkt = kEnd >> 6;

    const int tid = threadIdx.x;
    const int lane = tid & 63, wave = tid >> 6;
    const int wr = wave >> 2, wc = wave & 3;

    const u16* __restrict__ Ab = A + (long long)bz * sAz + (long long)r0 * K;
    const u16* __restrict__ Bb = B + (long long)bz * sBz + (long long)c0 * K;

    // staging: thread t fills LDS linearly (row = chunk*64 + tid/8, k-chunk =
    // tid&7); global source k-chunk pre-swizzled (inverse of the read XOR).
    const int srow = tid >> 3;
    const int skc8 = (((tid & 7) ^ ((tid >> 4) & 7))) * 8;

    // fragment-read constants (read XOR = (lane>>1)&7, matches stage inverse)
    const int lr = lane & 15;
    const int xr = (lane >> 1) & 7;
    const int kof0 = (((lane >> 4) + 0) ^ xr) * 8;   // k-half 0
    const int kof1 = (((lane >> 4) + 4) ^ xr) * 8;   // k-half 1

    f32x4 acc[8][4];
    #pragma unroll
    for (int i = 0; i < 8; ++i)
        #pragma unroll
        for (int j = 0; j < 4; ++j)
            acc[i][j] = (f32x4){0.f, 0.f, 0.f, 0.f};

    // prologue: tile0's 8 lines, A1,A3 last; leave A1,A3 in flight
    #pragma unroll
    for (int r = 0; r < 4; ++r)
        GLL16(Bb + (long long)(r * 64 + srow) * K + skc8, Bs + r * 4096 + tid * 8);
    GLL16(Ab + (long long)(0 * 64 + srow) * K + skc8, As + 0 * 4096 + tid * 8);
    GLL16(Ab + (long long)(2 * 64 + srow) * K + skc8, As + 2 * 4096 + tid * 8);
    GLL16(Ab + (long long)(1 * 64 + srow) * K + skc8, As + 1 * 4096 + tid * 8);
    GLL16(Ab + (long long)(3 * 64 + srow) * K + skc8, As + 3 * 4096 + tid * 8);
    asm volatile("s_waitcnt vmcnt(2)" ::: "memory");
    __builtin_amdgcn_s_barrier();

    for (int kt = 0; kt < nkt; ++kt) {
        const int buf = kt & 1;
        const u16* asb = As + buf * 16384;
        const u16* bsb = Bs + buf * 16384;
        u16* asn = As + (buf ^ 1) * 16384;
        u16* bsn = Bs + (buf ^ 1) * 16384;
        const long long kbn = (long long)(kt + 1) * 64 + skc8;
        const bool pf = (kt + 1 < nkt);
        bf16x8 bc[2][4];                     // B frags cached across rq pair
        #pragma unroll
        for (int ph = 0; ph < 2; ++ph) {
            const int rq = ph;
            const int ab0 = wr * 128 + rq * 64;
            bf16x8 a0[4], a1[4];
            #pragma unroll
            for (int i = 0; i < 4; ++i) {
                const int row = (ab0 + i * 16 + lr) * 64;
                a0[i] = *(const bf16x8*)&asb[row + kof0];
                a1[i] = *(const bf16x8*)&asb[row + kof1];
            }
            if (rq == 0) {
                #pragma unroll
                for (int j = 0; j < 4; ++j) {
                    const int row = (wc * 64 + j * 16 + lr) * 64;
                    bc[0][j] = *(const bf16x8*)&bsb[row + kof0];
                    bc[1][j] = *(const bf16x8*)&bsb[row + kof1];
                }
            }
            if (pf) {
                if (ph == 0) {
                    GLL16(Ab + (long long)(0 * 64 + srow) * K + kbn, asn + 0 * 4096 + tid * 8);
                    GLL16(Ab + (long long)(2 * 64 + srow) * K + kbn, asn + 2 * 4096 + tid * 8);
                    GLL16(Bb + (long long)(0 * 64 + srow) * K + kbn, bsn + 0 * 4096 + tid * 8);
                    GLL16(Bb + (long long)(1 * 64 + srow) * K + kbn, bsn + 1 * 4096 + tid * 8);
                } else {
                    GLL16(Bb + (long long)(2 * 64 + srow) * K + kbn, bsn + 2 * 4096 + tid * 8);
                    GLL16(Bb + (long long)(3 * 64 + srow) * K + kbn, bsn + 3 * 4096 + tid * 8);
                    GLL16(Ab + (long long)(1 * 64 + srow) * K + kbn, asn + 1 * 4096 + tid * 8);
                    GLL16(Ab + (long long)(3 * 64 + srow) * K + kbn, asn + 3 * 4096 + tid * 8);
                }
            }
            // NO pre-MFMA drain: compiler emits counted lgkmcnt between
            // ds_read and dependent MFMA (m97 mechanism) -> intra-wave
            // read/MFMA overlap.
            __builtin_amdgcn_s_setprio(1);
            #pragma unroll
            for (int i = 0; i < 4; ++i)
                #pragma unroll
                for (int j = 0; j < 4; ++j) {
                    acc[rq * 4 + i][j] = __builtin_amdgcn_mfma_f32_16x16x32_bf16(
                        a0[i], bc[0][j], acc[rq * 4 + i][j], 0, 0, 0);
                    acc[rq * 4 + i][j] = __builtin_amdgcn_mfma_f32_16x16x32_bf16(
                        a1[i], bc[1][j], acc[rq * 4 + i][j], 0, 0, 0);
                }
            __builtin_amdgcn_s_setprio(0);
            // phase-end: counted vmcnt (publish ledger) + lgkm drain (free by
            // now) in ONE wait, then barrier. "memory" clobber anchors all
            // memory ops on this side of the barrier.
            if (ph == 0) {
                if (pf) asm volatile("s_waitcnt vmcnt(4) lgkmcnt(0)" ::: "memory");
                else    asm volatile("s_waitcnt vmcnt(0) lgkmcnt(0)" ::: "memory");
            } else {
                if (pf) asm volatile("s_waitcnt vmcnt(2) lgkmcnt(0)" ::: "memory");
                else    asm volatile("s_waitcnt lgkmcnt(0)" ::: "memory");
            }
            __builtin_amdgcn_s_barrier();
        }
    }

    // output routing (uniform per block)
    void* Dp = D0;
    const float* bp_ = bias0;
    int ldD = N, cbase = c0, sel = 0;
    if (EPI == 0) {
        sel = bx >> 2;                 // 4 tiles of 256 per 1024-col group
        Dp  = (sel == 0) ? D0 : (sel == 1) ? D1 : D2;
        bp_ = (sel == 0) ? bias0 : (sel == 1) ? bias1 : bias2;
        ldD = 1024;
        cbase = c0 & 1023;
    }

    // epilogue: C/D layout col=lane&15, row=(lane>>4)*4+reg
    const int rl = (lane >> 4) * 4, cl = lane & 15;
    const int grb = r0 + wr * 128;
    const int gcb = cbase + wc * 64;

    if (EPI == 0 && sel == 2) {
        // v group: bias + rotate + TRANSPOSED store into vT[b][c][t]
        #pragma unroll
        for (int ai = 0; ai < 8; ++ai) {
            #pragma unroll
            for (int bj = 0; bj < 4; ++bj) {
                const int gr0 = grb + ai * 16 + rl;       // 4-aligned t base
                const int gcd = gcb + bj * 16 + cl;       // v column
                u16 pk[4];
                #pragma unroll
                for (int v = 0; v < 4; ++v) {
                    const int gr = gr0 + v;
                    float my = acc[ai][bj][v] + bp_[gcd];
                    float other = __shfl_xor(my, 1);
                    u32 csn = cossin[(long long)gr * 512 + (gcd >> 1)];
                    float cs = b2f((u16)(csn & 0xffff)), sn = b2f((u16)(csn >> 16));
                    float res = (gcd & 1) ? (sn * other + cs * my)
                                          : (cs * my - sn * other);
                    pk[v] = f2b(res);
                }
                const int bb = gr0 >> 10, tt = gr0 & 1023;
                u16* dst = (u16*)Dp + ((((long long)bb << 10) + gcd) << 10) + tt;
                uint2 pw;
                pw.x = (u32)pk[0] | ((u32)pk[1] << 16);
                pw.y = (u32)pk[2] | ((u32)pk[3] << 16);
                *(uint2*)dst = pw;
            }
        }
        return;
    }

    #pragma unroll
    for (int ai = 0; ai < 8; ++ai) {
        #pragma unroll
        for (int bj = 0; bj < 4; ++bj) {
            const int gr0 = grb + ai * 16 + rl;
            const int gcd = gcb + bj * 16 + cl;
            #pragma unroll
            for (int v = 0; v < 4; ++v) {
                const int gr = gr0 + v;
                float val = acc[ai][bj][v];
                const long long o = (long long)bz * sDz + (long long)gr * ldD + gcd;
                if (EPI == 0) {
                    float my = val + bp_[gcd];
                    float other = __shfl_xor(my, 1);
                    u32 csn = cossin[(long long)gr * 512 + (gcd >> 1)];
                    float cs = b2f((u16)(csn & 0xffff)), sn = b2f((u16)(csn >> 16));
                    float res = (gcd & 1) ? (sn * other + cs * my)
                                          : (cs * my - sn * other);
                    ((u16*)Dp)[o] = f2b(res);
                } else if (EPI == 1) {
                    float xs = val * scale;
                    float r = (gcd <= gr) ? ((xs > 15.f) ? xs : log1pf(__expf(xs))) : 0.f;
                    ((u16*)Dp)[o] = f2b(r);
                } else if (EPI == 2) {
                    float my = val;
                    float other = __shfl_xor(my, 1);
                    u32 csn = cossin[((long long)((bz << 10) + gr)) * 512 + (gcd >> 1)];
                    float cs = b2f((u16)(csn & 0xffff)), sn = b2f((u16)(csn >> 16));
                    float res = (gcd & 1) ? (cs * my - sn * other)
                                          : (cs * my + sn * other);
                    ((u16*)Dp)[o] = f2b(res);
                } else {
                    ((float*)Dp)[o] = val + bp_[gcd];
                }
            }
        }
    }
}

// ---------------------------------------------------------------------------
// fp32 -> bf16 conversion, vectorized x4
// ---------------------------------------------------------------------------
__global__ void f2b_kern(const float* __restrict__ in, u16* __restrict__ out, int n4) {
    int i = blockIdx.x * blockDim.x + threadIdx.x;
    if (i >= n4) return;
    float4 f = ((const float4*)in)[i];
    uint2 o;
    o.x = (u32)f2b(f.x) | ((u32)f2b(f.y) << 16);
    o.y = (u32)f2b(f.z) | ((u32)f2b(f.w) << 16);
    ((uint2*)out)[i] = o;
}

// 4 weight matrices in one launch (blockIdx.y selects)
__global__ void f2b_w4(const float* __restrict__ a, const float* __restrict__ b,
                       const float* __restrict__ c, const float* __restrict__ d,
                       u16* __restrict__ oa, u16* __restrict__ ob,
                       u16* __restrict__ oc, u16* __restrict__ od, int n4) {
    int i = blockIdx.x * blockDim.x + threadIdx.x;
    if (i >= n4) return;
    const float* src = (blockIdx.y == 0) ? a : (blockIdx.y == 1) ? b
                     : (blockIdx.y == 2) ? c : d;
    u16* dst = (blockIdx.y == 0) ? oa : (blockIdx.y == 1) ? ob
             : (blockIdx.y == 2) ? oc : od;
    float4 f = ((const float4*)src)[i];
    uint2 o;
    o.x = (u32)f2b(f.x) | ((u32)f2b(f.y) << 16);
    o.y = (u32)f2b(f.z) | ((u32)f2b(f.w) << 16);
    ((uint2*)dst)[i] = o;
}

// ---------------------------------------------------------------------------
// Angle suffix-sum (angle[t] = sum_{s>=t} emb[idx[s]]) in 2 phases; phase 2
// computes its own chunk-suffix (no serial scan dispatch) and emits packed
// bf16 {cos, sin}.
// ---------------------------------------------------------------------------
#define TT 1024
#define CC2 512
#define NCH 32
#define CL 32

__global__ void angle_partial(const int* __restrict__ idx, const float* __restrict__ emb,
                              float* __restrict__ partial) {
    int b = blockIdx.x >> 5, ch = blockIdx.x & 31;
    int c = threadIdx.x;               // 0..511
    float s = 0.f;
    int tb = ch * CL;
    for (int t = 0; t < CL; t++) {
        int row = idx[b * TT + tb + t];
        s += emb[(long long)row * CC2 + c];
    }
    partial[((long long)b * NCH + ch) * CC2 + c] = s;
}

__global__ void angle_final(const int* __restrict__ idx, const float* __restrict__ emb,
                            const float* __restrict__ partial,
                            u32* __restrict__ cossin) {
    int b = blockIdx.x >> 5, ch = blockIdx.x & 31;
    int c = threadIdx.x;
    // exclusive suffix over chunks after ch (same accumulation order as the
    // old serial scan: descending cc)
    float run = 0.f;
    for (int cc = NCH - 1; cc > ch; cc--)
        run += partial[((long long)b * NCH + cc) * CC2 + c];
    for (int t = CL - 1; t >= 0; t--) {
        int tt = ch * CL + t;
        int row = idx[b * TT + tt];
        run += emb[(long long)row * CC2 + c];
        float sn, cs;
        __sincosf(run, &sn, &cs);
        cossin[((long long)b * TT + tt) * CC2 + c] = (u32)f2b(cs) | ((u32)f2b(sn) << 16);
    }
}

// ---------------------------------------------------------------------------
extern "C" void kernel_launch(void* const* d_in, const int* in_sizes, int n_in,
                              void* d_out, int out_size, void* d_ws, size_t ws_size,
                              hipStream_t stream) {
    const int Bn = 16, T = 1024, C = 1024;
    const long long TC = (long long)T * C;
    const size_t nx = (size_t)Bn * T * C;          // 16,777,216
    const size_t npairs = nx / 2;                  // 8,388,608

    const float* x   = (const float*)d_in[0];
    const int*   idx = (const int*)d_in[1];
    const float* Wk  = (const float*)d_in[2];
    const float* bk  = (const float*)d_in[3];
    const float* Wq  = (const float*)d_in[4];
    const float* bq  = (const float*)d_in[5];
    const float* Wv  = (const float*)d_in[6];
    const float* bv  = (const float*)d_in[7];
    const float* Wp  = (const float*)d_in[8];
    const float* bp  = (const float*)d_in[9];
    const float* emb = (const float*)d_in[10];
    float* out = (float*)d_out;

    // one-time: allow 128 KiB dynamic LDS on the 256^2 kernels
    static bool s_attr = false;
    if (!s_attr) {
        auto* k0 = gemm256<0, 0>;
        auto* k1 = gemm256<1, 1>;
        auto* k2 = gemm256<2, 2>;
        auto* k3 = gemm256<3, 0>;
        (void)hipFuncSetAttribute(reinterpret_cast<const void*>(k0),
                                  hipFuncAttributeMaxDynamicSharedMemorySize, 131072);
        (void)hipFuncSetAttribute(reinterpret_cast<const void*>(k1),
                                  hipFuncAttributeMaxDynamicSharedMemorySize, 131072);
        (void)hipFuncSetAttribute(reinterpret_cast<const void*>(k2),
                                  hipFuncAttributeMaxDynamicSharedMemorySize, 131072);
        (void)hipFuncSetAttribute(reinterpret_cast<const void*>(k3),
                                  hipFuncAttributeMaxDynamicSharedMemorySize, 131072);
        s_attr = true;
    }

    // workspace (~171 MB)
    u16* xb  = (u16*)d_ws;          // x bf16; aliased as wei after QKV
    u16* kb  = xb + nx;             // k (rotated by QKV epilogue)
    u16* qb  = kb + nx;             // q (rotated); y after attn GEMM
    u16* vT  = qb + nx;             // v rotated+transposed [B][C][T]
    u32* cossin = (u32*)(vT + nx);  // [B][T][512] packed bf16 {cos,sin}
    u16* Wall = (u16*)(cossin + npairs);           // [3072][1024] = Wk|Wq|Wv
    u16* Wpb  = Wall + (size_t)3 * C * C;
    float* partial = (float*)(Wpb + (size_t)C * C);  // [B][32][512]
    u16* wei = xb;                  // alias (x dead after QKV)

    // 1) conversions to bf16
    f2b_kern<<<(int)(nx / 4 / 256), 256, 0, stream>>>(x, xb, (int)(nx / 4));
    f2b_w4<<<dim3(C * C / 4 / 256, 4), 256, 0, stream>>>(
        Wk, Wq, Wv, Wp, Wall, Wall + (size_t)C * C, Wall + (size_t)2 * C * C, Wpb,
        C * C / 4);

    // 2) angle suffix-sum -> packed cos/sin (2 dispatches; suffix computed
    //    in-kernel, serial scan dispatch removed)
    angle_partial<<<Bn * NCH, 512, 0, stream>>>(idx, emb, partial);
    angle_final<<<Bn * NCH, 512, 0, stream>>>(idx, emb, partial, cossin);

    // 3) fused QKV projection: M=16384, N=3072, K=1024; 64x12 tiles.
    gemm256<0, 0><<<768, 512, 131072, stream>>>(
        xb, 0, Wall, 0, kb, qb, vT, 0, bk, bq, bv, cossin,
        3 * C, C, 1.f, 12);

    // 4) wei = softplus(k @ q^T / 32), causal: 16 batches x 10 tril tiles
    gemm256<1, 1><<<160, 512, 131072, stream>>>(
        kb, TC, qb, TC, wei, nullptr, nullptr, (long long)T * T,
        nullptr, nullptr, nullptr, nullptr, T, C, 0.03125f, 0);

    // 5) attn = wei @ v, inverse-rotation epilogue -> y (qb);
    //    16 batches x 16 tiles, K truncated at (by+1)*256 (causal)
    gemm256<2, 2><<<256, 512, 131072, stream>>>(
        wei, (long long)T * T, vT, (long long)C * T, qb, nullptr, nullptr, TC,
        nullptr, nullptr, nullptr, cossin, C, T, 1.f, 0);

    // 6) final projection -> f32 out: 64x4 tiles.
    gemm256<3, 0><<<256, 512, 131072, stream>>>(
        qb, 0, Wpb, 0, out, nullptr, nullptr, 0, bp, nullptr, nullptr, nullptr,
        C, C, 1.f, 4);
}

// Round 8
// 492.886 us; speedup vs baseline: 1.1995x; 1.1831x over previous
//
#include <hip/hip_runtime.h>
#include <math.h>

typedef unsigned short u16;
typedef unsigned int u32;
typedef __bf16 bf16x8 __attribute__((ext_vector_type(8)));
typedef float f32x4 __attribute__((ext_vector_type(4)));

__device__ __forceinline__ u16 f2b(float f) {
    u32 u = __float_as_uint(f);
    return (u16)((u + 0x7FFFu + ((u >> 16) & 1u)) >> 16);
}
__device__ __forceinline__ float b2f(u16 h) {
    return __uint_as_float(((u32)h) << 16);
}

// async global->LDS, 16B per lane. LDS dest is wave-uniform base + lane*16.
#define GLL16(gp, lp)                                                          \
    __builtin_amdgcn_global_load_lds(                                          \
        (__attribute__((address_space(1))) void*)(const_cast<u16*>(gp)),       \
        (__attribute__((address_space(3))) void*)(lp), 16, 0, 0)

// ---------------------------------------------------------------------------
// 256x256 NT GEMM, TWO phases per K-tile (32-MFMA clusters), one barrier per
// phase. 8 waves (2M x 4N), BK=64, LDS 128 KiB (2 dbuf x (A 32K + B 32K)).
// K-LOOP IS THE r5 STRUCTURE VERBATIM (best measured: 466 us total, QKV 814
// TF; r6/r7 schedule variants both regressed).
//
// Phase p = rq (acc row-quadrant). rq=0: read 8 A-frags (chunk 2wr) + 8
// B-frags (both k-halves, reg-cached); rq=1: read 8 A-frags (chunk 2wr+1),
// reuse cached B. lgkmcnt(0)+sched_barrier pin before the 32-MFMA cluster
// (rule #18; r7 proved removing it regresses), setprio(1) around MFMA (T5),
// counted vmcnt at phase end (T4), one s_barrier per phase.
//
// Counted-vmcnt ledger (FIFO-audited): ph0 issues next A0,A2,B0,B1; ph1
// issues next B2,B3,A1,A3. ph0-end vmcnt(4) retires this tile's A1,A3;
// ph1-end vmcnt(2) retires next tile's A0,A2,B0..B3 (A1,A3 stay in flight).
// Tails: last tile ph0-end vmcnt(0). Prologue: 8 lines, A1,A3 last, vmcnt(2).
//
// LDS swizzle (T2): logical k-chunk kc at physical chunk kc ^ ((row>>1)&7)
// via inverse-swizzled GLOBAL source (GLL dest linear, rule #21); reads
// apply the same XOR. 0 conflicts (verified r1-r7).
//
// NEW (r8): wide-store epilogue. Each wave transposes its 128x64 acc through
// a PRIVATE 16x68 f32 LDS slab (pad 68: 16B-aligned rows, <=2-way banks) in
// 8 chunks; re-read row-major so a thread owns 8 consecutive output columns:
// rotation pairs are thread-internal (no shfl), bias/cossin are float4/uint4
// loads, stores are 16B packed (8 lanes x 16B = 128B contiguous per row).
// Replaces 128 scalar 2-4B stores + 128 shfl_xor per thread.
//
// MODE 0: 2-D row x col grid, XCD-swizzled by row tile (QKV / proj), bz=0.
// MODE 1: batch x tril-tile grid (wei): bz=n&15, t=n>>4 in 0..9 lower-tri.
// MODE 2: batch x full 4x4 grid (attn): kEnd=(by+1)*256 causal truncation.
// EPI  0: +bias, pair-rotate -> bf16 (k/q/vT split; v stored transposed)
//      1: softplus(scale*x) causal-masked -> bf16
//      2: inverse pair-rotate -> bf16
//      3: +bias -> f32
// ---------------------------------------------------------------------------
template <int EPI, int MODE>
__global__ __launch_bounds__(512, 2) void gemm256(
    const u16* __restrict__ A, long long sAz,
    const u16* __restrict__ B, long long sBz,
    void* __restrict__ D0, void* __restrict__ D1, void* __restrict__ D2,
    long long sDz,
    const float* __restrict__ bias0, const float* __restrict__ bias1,
    const float* __restrict__ bias2,
    const u32* __restrict__ cossin,
    int N, int K, float scale, int WB)
{
    extern __shared__ u16 lds[];
    u16* const As = lds;                    // [2][4 chunks][64 rows][64]
    u16* const Bs = lds + 2 * 256 * 64;

    int bx, by, bz;
    if (MODE == 0) {
        const int n = blockIdx.x;
        const int xcd = n & 7, m = n >> 3;
        by = xcd + 8 * (m / WB);
        bx = m % WB;
        bz = 0;
    } else if (MODE == 1) {
        const int n = blockIdx.x;
        bz = n & 15;
        const int t = n >> 4;               // 0..9 lower-triangular tile
        by = (t >= 1) + (t >= 3) + (t >= 6);
        bx = t - ((by * (by + 1)) >> 1);
    } else {
        const int n = blockIdx.x;
        bz = n & 15;
        const int t = n >> 4;               // 0..15
        by = t >> 2;
        bx = t & 3;
    }
    const int r0 = by * 256, c0 = bx * 256;

    const int kEnd = (MODE == 2) ? (((by + 1) * 256) < K ? ((by + 1) * 256) : K) : K;
    const int nkt = kEnd >> 6;

    const int tid = threadIdx.x;
    const int lane = tid & 63, wave = tid >> 6;
    const int wr = wave >> 2, wc = wave & 3;

    const u16* __restrict__ Ab = A + (long long)bz * sAz + (long long)r0 * K;
    const u16* __restrict__ Bb = B + (long long)bz * sBz + (long long)c0 * K;

    // staging: thread t fills LDS linearly (row = chunk*64 + tid/8, k-chunk =
    // tid&7); global source k-chunk pre-swizzled (inverse of the read XOR).
    const int srow = tid >> 3;
    const int skc8 = (((tid & 7) ^ ((tid >> 4) & 7))) * 8;

    // fragment-read constants (read XOR = (lane>>1)&7, matches stage inverse)
    const int lr = lane & 15;
    const int xr = (lane >> 1) & 7;
    const int kof0 = (((lane >> 4) + 0) ^ xr) * 8;   // k-half 0
    const int kof1 = (((lane >> 4) + 4) ^ xr) * 8;   // k-half 1

    f32x4 acc[8][4];
    #pragma unroll
    for (int i = 0; i < 8; ++i)
        #pragma unroll
        for (int j = 0; j < 4; ++j)
            acc[i][j] = (f32x4){0.f, 0.f, 0.f, 0.f};

    // prologue: tile0's 8 lines, A1,A3 last; leave A1,A3 in flight
    #pragma unroll
    for (int r = 0; r < 4; ++r)
        GLL16(Bb + (long long)(r * 64 + srow) * K + skc8, Bs + r * 4096 + tid * 8);
    GLL16(Ab + (long long)(0 * 64 + srow) * K + skc8, As + 0 * 4096 + tid * 8);
    GLL16(Ab + (long long)(2 * 64 + srow) * K + skc8, As + 2 * 4096 + tid * 8);
    GLL16(Ab + (long long)(1 * 64 + srow) * K + skc8, As + 1 * 4096 + tid * 8);
    GLL16(Ab + (long long)(3 * 64 + srow) * K + skc8, As + 3 * 4096 + tid * 8);
    asm volatile("s_waitcnt vmcnt(2)" ::: "memory");
    __builtin_amdgcn_s_barrier();

    for (int kt = 0; kt < nkt; ++kt) {
        const int buf = kt & 1;
        const u16* asb = As + buf * 16384;
        const u16* bsb = Bs + buf * 16384;
        u16* asn = As + (buf ^ 1) * 16384;
        u16* bsn = Bs + (buf ^ 1) * 16384;
        const long long kbn = (long long)(kt + 1) * 64 + skc8;
        const bool pf = (kt + 1 < nkt);
        bf16x8 bc[2][4];                     // B frags cached across rq pair
        #pragma unroll
        for (int ph = 0; ph < 2; ++ph) {
            const int rq = ph;
            const int ab0 = wr * 128 + rq * 64;
            bf16x8 a0[4], a1[4];
            #pragma unroll
            for (int i = 0; i < 4; ++i) {
                const int row = (ab0 + i * 16 + lr) * 64;
                a0[i] = *(const bf16x8*)&asb[row + kof0];
                a1[i] = *(const bf16x8*)&asb[row + kof1];
            }
            if (rq == 0) {
                #pragma unroll
                for (int j = 0; j < 4; ++j) {
                    const int row = (wc * 64 + j * 16 + lr) * 64;
                    bc[0][j] = *(const bf16x8*)&bsb[row + kof0];
                    bc[1][j] = *(const bf16x8*)&bsb[row + kof1];
                }
            }
            if (pf) {
                if (ph == 0) {
                    GLL16(Ab + (long long)(0 * 64 + srow) * K + kbn, asn + 0 * 4096 + tid * 8);
                    GLL16(Ab + (long long)(2 * 64 + srow) * K + kbn, asn + 2 * 4096 + tid * 8);
                    GLL16(Bb + (long long)(0 * 64 + srow) * K + kbn, bsn + 0 * 4096 + tid * 8);
                    GLL16(Bb + (long long)(1 * 64 + srow) * K + kbn, bsn + 1 * 4096 + tid * 8);
                } else {
                    GLL16(Bb + (long long)(2 * 64 + srow) * K + kbn, bsn + 2 * 4096 + tid * 8);
                    GLL16(Bb + (long long)(3 * 64 + srow) * K + kbn, bsn + 3 * 4096 + tid * 8);
                    GLL16(Ab + (long long)(1 * 64 + srow) * K + kbn, asn + 1 * 4096 + tid * 8);
                    GLL16(Ab + (long long)(3 * 64 + srow) * K + kbn, asn + 3 * 4096 + tid * 8);
                }
            }
            asm volatile("s_waitcnt lgkmcnt(0)" ::: "memory");
            __builtin_amdgcn_sched_barrier(0);   // rule #18: pin MFMA after wait
            __builtin_amdgcn_s_setprio(1);
            #pragma unroll
            for (int i = 0; i < 4; ++i)
                #pragma unroll
                for (int j = 0; j < 4; ++j) {
                    acc[rq * 4 + i][j] = __builtin_amdgcn_mfma_f32_16x16x32_bf16(
                        a0[i], bc[0][j], acc[rq * 4 + i][j], 0, 0, 0);
                    acc[rq * 4 + i][j] = __builtin_amdgcn_mfma_f32_16x16x32_bf16(
                        a1[i], bc[1][j], acc[rq * 4 + i][j], 0, 0, 0);
                }
            __builtin_amdgcn_s_setprio(0);
            if (ph == 0) {
                if (pf) asm volatile("s_waitcnt vmcnt(4)" ::: "memory");
                else    asm volatile("s_waitcnt vmcnt(0)" ::: "memory");
            } else if (pf) {
                asm volatile("s_waitcnt vmcnt(2)" ::: "memory");
            }
            __builtin_amdgcn_s_barrier();
        }
    }

    // output routing (uniform per block)
    void* Dp = D0;
    const float* bp_ = bias0;
    int ldD = N, cbase = c0, sel = 0;
    if (EPI == 0) {
        sel = bx >> 2;                 // 4 tiles of 256 per 1024-col group
        Dp  = (sel == 0) ? D0 : (sel == 1) ? D1 : D2;
        bp_ = (sel == 0) ? bias0 : (sel == 1) ? bias1 : bias2;
        ldD = 1024;
        cbase = c0 & 1023;
    }

    // epilogue geometry: C/D layout col=lane&15, row=(lane>>4)*4+reg
    const int rl = (lane >> 4) * 4, cl = lane & 15;
    const int grb = r0 + wr * 128;
    const int gcb = cbase + wc * 64;

    if (EPI == 0 && sel == 2) {
        // v group: bias + rotate + TRANSPOSED store into vT[b][c][t]
        // (already-wide path: uint2 stores down t; unchanged)
        #pragma unroll
        for (int ai = 0; ai < 8; ++ai) {
            #pragma unroll
            for (int bj = 0; bj < 4; ++bj) {
                const int gr0 = grb + ai * 16 + rl;       // 4-aligned t base
                const int gcd = gcb + bj * 16 + cl;       // v column
                u16 pk[4];
                #pragma unroll
                for (int v = 0; v < 4; ++v) {
                    const int gr = gr0 + v;
                    float my = acc[ai][bj][v] + bp_[gcd];
                    float other = __shfl_xor(my, 1);
                    u32 csn = cossin[(long long)gr * 512 + (gcd >> 1)];
                    float cs = b2f((u16)(csn & 0xffff)), sn = b2f((u16)(csn >> 16));
                    float res = (gcd & 1) ? (sn * other + cs * my)
                                          : (cs * my - sn * other);
                    pk[v] = f2b(res);
                }
                const int bb = gr0 >> 10, tt = gr0 & 1023;
                u16* dst = (u16*)Dp + ((((long long)bb << 10) + gcd) << 10) + tt;
                uint2 pw;
                pw.x = (u32)pk[0] | ((u32)pk[1] << 16);
                pw.y = (u32)pk[2] | ((u32)pk[3] << 16);
                *(uint2*)dst = pw;
            }
        }
        return;
    }

    // ---------- wide-store epilogue via per-wave LDS transpose ----------
    // Wave-private slab: 16 rows x 68 f32 (pad 68 -> 16B-aligned rows,
    // <=2-way banks on both write and read). Loop completed: all loop LDS
    // reads drained at the final barrier; slabs are wave-private (no sync).
    {
        float* slab = (float*)lds + (size_t)wave * (16 * 68);
        #pragma unroll
        for (int ai = 0; ai < 8; ++ai) {
            #pragma unroll
            for (int bj = 0; bj < 4; ++bj)
                #pragma unroll
                for (int v = 0; v < 4; ++v)
                    slab[(rl + v) * 68 + bj * 16 + cl] = acc[ai][bj][v];
            asm volatile("s_waitcnt lgkmcnt(0)" ::: "memory");  // writes -> reads
            #pragma unroll
            for (int half = 0; half < 2; ++half) {
                const int rloc = half * 8 + (lane >> 3);      // 0..15
                const int c0l  = (lane & 7) * 8;              // 0..56
                const int gr   = grb + ai * 16 + rloc;
                const int gcd0 = gcb + c0l;                   // 8-aligned col
                float v8[8];
                #pragma unroll
                for (int e = 0; e < 8; ++e)
                    v8[e] = slab[rloc * 68 + c0l + e];
                const long long o = (long long)bz * sDz + (long long)gr * ldD + gcd0;
                if (EPI == 0) {
                    // k/q: +bias then pair-rotate (pairs are thread-internal)
                    const float4 ba = *(const float4*)&bp_[gcd0];
                    const float4 bbv = *(const float4*)&bp_[gcd0 + 4];
                    const float bb8[8] = {ba.x, ba.y, ba.z, ba.w,
                                          bbv.x, bbv.y, bbv.z, bbv.w};
                    const uint4 cs4 = *(const uint4*)&cossin[(long long)gr * 512 + (gcd0 >> 1)];
                    const u32 csw[4] = {cs4.x, cs4.y, cs4.z, cs4.w};
                    u16 pk[8];
                    #pragma unroll
                    for (int p = 0; p < 4; ++p) {
                        const float e0 = v8[2 * p] + bb8[2 * p];
                        const float e1 = v8[2 * p + 1] + bb8[2 * p + 1];
                        const float cs = b2f((u16)(csw[p] & 0xffff));
                        const float sn = b2f((u16)(csw[p] >> 16));
                        pk[2 * p]     = f2b(cs * e0 - sn * e1);
                        pk[2 * p + 1] = f2b(sn * e0 + cs * e1);
                    }
                    uint4 pw;
                    pw.x = (u32)pk[0] | ((u32)pk[1] << 16);
                    pw.y = (u32)pk[2] | ((u32)pk[3] << 16);
                    pw.z = (u32)pk[4] | ((u32)pk[5] << 16);
                    pw.w = (u32)pk[6] | ((u32)pk[7] << 16);
                    *(uint4*)&((u16*)Dp)[o] = pw;
                } else if (EPI == 1) {
                    u16 pk[8];
                    #pragma unroll
                    for (int e = 0; e < 8; ++e) {
                        const float xs = v8[e] * scale;
                        const float r = ((gcd0 + e) <= gr)
                            ? ((xs > 15.f) ? xs : log1pf(__expf(xs))) : 0.f;
                        pk[e] = f2b(r);
                    }
                    uint4 pw;
                    pw.x = (u32)pk[0] | ((u32)pk[1] << 16);
                    pw.y = (u32)pk[2] | ((u32)pk[3] << 16);
                    pw.z = (u32)pk[4] | ((u32)pk[5] << 16);
                    pw.w = (u32)pk[6] | ((u32)pk[7] << 16);
                    *(uint4*)&((u16*)Dp)[o] = pw;
                } else if (EPI == 2) {
                    // inverse rotation, pairs thread-internal
                    const uint4 cs4 = *(const uint4*)
                        &cossin[((long long)((bz << 10) + gr)) * 512 + (gcd0 >> 1)];
                    const u32 csw[4] = {cs4.x, cs4.y, cs4.z, cs4.w};
                    u16 pk[8];
                    #pragma unroll
                    for (int p = 0; p < 4; ++p) {
                        const float e0 = v8[2 * p], e1 = v8[2 * p + 1];
                        const float cs = b2f((u16)(csw[p] & 0xffff));
                        const float sn = b2f((u16)(csw[p] >> 16));
                        pk[2 * p]     = f2b(cs * e0 + sn * e1);
                        pk[2 * p + 1] = f2b(cs * e1 - sn * e0);
                    }
                    uint4 pw;
                    pw.x = (u32)pk[0] | ((u32)pk[1] << 16);
                    pw.y = (u32)pk[2] | ((u32)pk[3] << 16);
                    pw.z = (u32)pk[4] | ((u32)pk[5] << 16);
                    pw.w = (u32)pk[6] | ((u32)pk[7] << 16);
                    *(uint4*)&((u16*)Dp)[o] = pw;
                } else {
                    const float4 ba = *(const float4*)&bp_[gcd0];
                    const float4 bbv = *(const float4*)&bp_[gcd0 + 4];
                    float4 s0, s1;
                    s0.x = v8[0] + ba.x;  s0.y = v8[1] + ba.y;
                    s0.z = v8[2] + ba.z;  s0.w = v8[3] + ba.w;
                    s1.x = v8[4] + bbv.x; s1.y = v8[5] + bbv.y;
                    s1.z = v8[6] + bbv.z; s1.w = v8[7] + bbv.w;
                    *(float4*)&((float*)Dp)[o]     = s0;
                    *(float4*)&((float*)Dp)[o + 4] = s1;
                }
            }
            asm volatile("s_waitcnt lgkmcnt(0)" ::: "memory");  // reads done before reuse
        }
    }
}

// ---------------------------------------------------------------------------
// Merged prep: x->bf16 (16384 blocks) | 4 weights->bf16 (4096) |
// angle partial sums (1024). One dispatch instead of three.
// ---------------------------------------------------------------------------
#define TT 1024
#define CC2 512
#define NCH 32
#define CL 32

__global__ void prep(const float* __restrict__ x,
                     const float* __restrict__ Wk, const float* __restrict__ Wq,
                     const float* __restrict__ Wv, const float* __restrict__ Wp,
                     u16* __restrict__ xb, u16* __restrict__ wall,
                     u16* __restrict__ wpb,
                     const int* __restrict__ idx, const float* __restrict__ emb,
                     float* __restrict__ partial)
{
    const int bid = blockIdx.x, tid = threadIdx.x;
    if (bid < 16384) {                       // x -> bf16 (float4/thread)
        const int i = bid * 256 + tid;
        float4 f = ((const float4*)x)[i];
        uint2 o;
        o.x = (u32)f2b(f.x) | ((u32)f2b(f.y) << 16);
        o.y = (u32)f2b(f.z) | ((u32)f2b(f.w) << 16);
        ((uint2*)xb)[i] = o;
    } else if (bid < 20480) {                // weights -> bf16
        const int s = bid - 16384;
        const int w = s >> 10;               // 0..3
        const int i = (s & 1023) * 256 + tid;
        const float* src = (w == 0) ? Wk : (w == 1) ? Wq : (w == 2) ? Wv : Wp;
        u16* dst = (w == 0) ? wall : (w == 1) ? wall + 1024 * 1024
                 : (w == 2) ? wall + 2 * 1024 * 1024 : wpb;
        float4 f = ((const float4*)src)[i];
        uint2 o;
        o.x = (u32)f2b(f.x) | ((u32)f2b(f.y) << 16);
        o.y = (u32)f2b(f.z) | ((u32)f2b(f.w) << 16);
        ((uint2*)dst)[i] = o;
    } else {                                 // angle partial sums
        const int s = bid - 20480;           // 0..1023
        const int b = s >> 6;
        const int r = s & 63;
        const int ch = r >> 1, half = r & 1;
        const int c = half * 256 + tid;      // 0..511
        float acc = 0.f;
        const int tb = ch * CL;
        for (int t = 0; t < CL; t++) {
            const int row = idx[b * TT + tb + t];
            acc += emb[(long long)row * CC2 + c];
        }
        partial[((long long)b * NCH + ch) * CC2 + c] = acc;
    }
}

__global__ void angle_final(const int* __restrict__ idx, const float* __restrict__ emb,
                            const float* __restrict__ partial,
                            u32* __restrict__ cossin) {
    int b = blockIdx.x >> 5, ch = blockIdx.x & 31;
    int c = threadIdx.x;
    // exclusive suffix over chunks after ch (same accumulation order as the
    // old serial scan: descending cc)
    float run = 0.f;
    for (int cc = NCH - 1; cc > ch; cc--)
        run += partial[((long long)b * NCH + cc) * CC2 + c];
    for (int t = CL - 1; t >= 0; t--) {
        int tt = ch * CL + t;
        int row = idx[b * TT + tt];
        run += emb[(long long)row * CC2 + c];
        float sn, cs;
        __sincosf(run, &sn, &cs);
        cossin[((long long)b * TT + tt) * CC2 + c] = (u32)f2b(cs) | ((u32)f2b(sn) << 16);
    }
}

// ---------------------------------------------------------------------------
extern "C" void kernel_launch(void* const* d_in, const int* in_sizes, int n_in,
                              void* d_out, int out_size, void* d_ws, size_t ws_size,
                              hipStream_t stream) {
    const int Bn = 16, T = 1024, C = 1024;
    const long long TC = (long long)T * C;
    const size_t nx = (size_t)Bn * T * C;          // 16,777,216
    const size_t npairs = nx / 2;                  // 8,388,608

    const float* x   = (const float*)d_in[0];
    const int*   idx = (const int*)d_in[1];
    const float* Wk  = (const float*)d_in[2];
    const float* bk  = (const float*)d_in[3];
    const float* Wq  = (const float*)d_in[4];
    const float* bq  = (const float*)d_in[5];
    const float* Wv  = (const float*)d_in[6];
    const float* bv  = (const float*)d_in[7];
    const float* Wp  = (const float*)d_in[8];
    const float* bp  = (const float*)d_in[9];
    const float* emb = (const float*)d_in[10];
    float* out = (float*)d_out;

    // one-time: allow 128 KiB dynamic LDS on the 256^2 kernels
    static bool s_attr = false;
    if (!s_attr) {
        auto* k0 = gemm256<0, 0>;
        auto* k1 = gemm256<1, 1>;
        auto* k2 = gemm256<2, 2>;
        auto* k3 = gemm256<3, 0>;
        (void)hipFuncSetAttribute(reinterpret_cast<const void*>(k0),
                                  hipFuncAttributeMaxDynamicSharedMemorySize, 131072);
        (void)hipFuncSetAttribute(reinterpret_cast<const void*>(k1),
                                  hipFuncAttributeMaxDynamicSharedMemorySize, 131072);
        (void)hipFuncSetAttribute(reinterpret_cast<const void*>(k2),
                                  hipFuncAttributeMaxDynamicSharedMemorySize, 131072);
        (void)hipFuncSetAttribute(reinterpret_cast<const void*>(k3),
                                  hipFuncAttributeMaxDynamicSharedMemorySize, 131072);
        s_attr = true;
    }

    // workspace (~171 MB)
    u16* xb  = (u16*)d_ws;          // x bf16; aliased as wei after QKV
    u16* kb  = xb + nx;             // k (rotated by QKV epilogue)
    u16* qb  = kb + nx;             // q (rotated); y after attn GEMM
    u16* vT  = qb + nx;             // v rotated+transposed [B][C][T]
    u32* cossin = (u32*)(vT + nx);  // [B][T][512] packed bf16 {cos,sin}
    u16* Wall = (u16*)(cossin + npairs);           // [3072][1024] = Wk|Wq|Wv
    u16* Wpb  = Wall + (size_t)3 * C * C;
    float* partial = (float*)(Wpb + (size_t)C * C);  // [B][32][512]
    u16* wei = xb;                  // alias (x dead after QKV)

    // 1) merged prep: conversions + angle partial sums (one dispatch)
    prep<<<21504, 256, 0, stream>>>(x, Wk, Wq, Wv, Wp, xb, Wall, Wpb,
                                    idx, emb, partial);

    // 2) angle suffix -> packed cos/sin
    angle_final<<<Bn * NCH, 512, 0, stream>>>(idx, emb, partial, cossin);

    // 3) fused QKV projection: M=16384, N=3072, K=1024; 64x12 tiles.
    gemm256<0, 0><<<768, 512, 131072, stream>>>(
        xb, 0, Wall, 0, kb, qb, vT, 0, bk, bq, bv, cossin,
        3 * C, C, 1.f, 12);

    // 4) wei = softplus(k @ q^T / 32), causal: 16 batches x 10 tril tiles
    gemm256<1, 1><<<160, 512, 131072, stream>>>(
        kb, TC, qb, TC, wei, nullptr, nullptr, (long long)T * T,
        nullptr, nullptr, nullptr, nullptr, T, C, 0.03125f, 0);

    // 5) attn = wei @ v, inverse-rotation epilogue -> y (qb);
    //    16 batches x 16 tiles, K truncated at (by+1)*256 (causal)
    gemm256<2, 2><<<256, 512, 131072, stream>>>(
        wei, (long long)T * T, vT, (long long)C * T, qb, nullptr, nullptr, TC,
        nullptr, nullptr, nullptr, cossin, C, T, 1.f, 0);

    // 6) final projection -> f32 out: 64x4 tiles.
    gemm256<3, 0><<<256, 512, 131072, stream>>>(
        qb, 0, Wpb, 0, out, nullptr, nullptr, 0, bp, nullptr, nullptr, nullptr,
        C, C, 1.f, 4);
}

// Round 9
// 428.029 us; speedup vs baseline: 1.3813x; 1.1515x over previous
//
#include <hip/hip_runtime.h>
#include <math.h>

typedef unsigned short u16;
typedef unsigned int u32;
typedef __bf16 bf16x8 __attribute__((ext_vector_type(8)));
typedef float f32x4 __attribute__((ext_vector_type(4)));

#define BM 128
#define BN 128
#define BK 32

__device__ __forceinline__ u16 f2b(float f) {
    u32 u = __float_as_uint(f);
    return (u16)((u + 0x7FFFu + ((u >> 16) & 1u)) >> 16);
}
__device__ __forceinline__ float b2f(u16 h) {
    return __uint_as_float(((u32)h) << 16);
}

// async global->LDS, 16B per lane. LDS dest is wave-uniform base + lane*16.
#define GLL16(gp, lp)                                                          \
    __builtin_amdgcn_global_load_lds(                                          \
        (__attribute__((address_space(1))) void*)(const_cast<u16*>(gp)),       \
        (__attribute__((address_space(3))) void*)(lp), 16, 0, 0)

// ---------------------------------------------------------------------------
// 128x128 m97-structure NT GEMM — used for wei / attn (small grids, short or
// tril K). 256 threads / 4 waves, VGPR ~100 -> ~3 resident blocks per CU:
// inter-block wave overlap (m114) hides the per-K-step barrier drain, which
// measured FASTER than the 256^2 1-resident-block kernel for these dispatches
// (r1->r2: +11 us when these moved to 256^2; reverted here).
// EPI 1 = softplus(scale*x) causal-masked -> bf16 (fast __logf form)
// EPI 2 = inverse pair-rotate -> bf16
// EARLY: skip fully-masked tiles. KLIM: truncate K at causal boundary.
// SWZ=1: batch-grouped XCD swizzle (bz = XCD), WB = 64.
// ---------------------------------------------------------------------------
template <int EPI, bool EARLY, bool KLIM, int SWZ, bool SPLIT>
__global__ __launch_bounds__(256) void gemm_nt(
    const u16* __restrict__ A, long long sAz,
    const u16* __restrict__ B, long long sBz,
    void* __restrict__ D0, void* __restrict__ D1, void* __restrict__ D2,
    long long sDz,
    const float* __restrict__ bias0, const float* __restrict__ bias1,
    const float* __restrict__ bias2,
    const u32* __restrict__ cossin,
    int M, int N, int K, float scale, int WB)
{
    int bx, by, bz;
    {
        const int n = blockIdx.x;
        const int xcd = n & 7, m = n >> 3;
        if (SWZ == 0) {
            by = xcd + 8 * (m / WB);
            bx = m % WB;
            bz = 0;
        } else {
            bz = xcd + 8 * (m / WB);
            const int w = m % WB;
            bx = w & 7;
            by = w >> 3;
        }
    }
    const int r0 = by * BM, c0 = bx * BN;

    if (EARLY && c0 >= r0 + BM) return;   // fully masked tile; never read later

    __shared__ __align__(16) u16 As[BM * BK];
    __shared__ __align__(16) u16 Bs[BN * BK];

    const int tid = threadIdx.x;
    const int lane = tid & 63, wave = tid >> 6;
    const int wm = (wave >> 1) * 64, wn = (wave & 1) * 64;

    const u16* Ab = A + (long long)bz * sAz + (long long)r0 * K;
    const u16* Bb = B + (long long)bz * sBz + (long long)c0 * K;

    const int ra0 = tid >> 2;          // row 0..63 (second issue: +64)
    const int ca0 = (tid & 3) * 8;     // k-chunk within row

    f32x4 acc[4][4];
    #pragma unroll
    for (int i = 0; i < 4; i++)
        #pragma unroll
        for (int j = 0; j < 4; j++)
            acc[i][j] = (f32x4){0.f, 0.f, 0.f, 0.f};

    const int kEnd = KLIM ? ((r0 + BM) < K ? (r0 + BM) : K) : K;

    for (int k0 = 0; k0 < kEnd; k0 += BK) {
        GLL16(Ab + (long long)ra0 * K + k0 + ca0,        &As[tid * 8]);
        GLL16(Ab + (long long)(ra0 + 64) * K + k0 + ca0, &As[(tid + 256) * 8]);
        GLL16(Bb + (long long)ra0 * K + k0 + ca0,        &Bs[tid * 8]);
        GLL16(Bb + (long long)(ra0 + 64) * K + k0 + ca0, &Bs[(tid + 256) * 8]);
        __syncthreads();

        bf16x8 af[4], bfv[4];
        #pragma unroll
        for (int i = 0; i < 4; i++) {
            af[i]  = *(const bf16x8*)&As[(wm + i * 16 + (lane & 15)) * BK + (lane >> 4) * 8];
            bfv[i] = *(const bf16x8*)&Bs[(wn + i * 16 + (lane & 15)) * BK + (lane >> 4) * 8];
        }
        #pragma unroll
        for (int i = 0; i < 4; i++)
            #pragma unroll
            for (int j = 0; j < 4; j++)
                acc[i][j] = __builtin_amdgcn_mfma_f32_16x16x32_bf16(af[i], bfv[j], acc[i][j], 0, 0, 0);
        __syncthreads();
    }

    void* Dp = D0;
    int ldD = N;
    const int cbase = c0;

    // epilogue: C/D layout col=lane&15, row=(lane>>4)*4+reg
    const int rl = (lane >> 4) * 4, cl = lane & 15;

    #pragma unroll
    for (int i = 0; i < 4; i++) {
        #pragma unroll
        for (int j = 0; j < 4; j++) {
            const int gr0 = r0 + wm + i * 16 + rl;
            const int gc  = wn + j * 16 + cl;
            const int gcd = cbase + gc;
            #pragma unroll
            for (int v = 0; v < 4; v++) {
                const int gr = gr0 + v;
                float val = acc[i][j][v];
                const long long o = (long long)bz * sDz + (long long)gr * ldD + gcd;
                if (EPI == 1) {
                    float xs = val * scale;
                    float r = (gcd <= gr) ? ((xs > 15.f) ? xs : __logf(1.f + __expf(xs))) : 0.f;
                    ((u16*)Dp)[o] = f2b(r);
                } else if (EPI == 2) {
                    float my = val;
                    float other = __shfl_xor(my, 1);
                    u32 csn = cossin[((long long)((bz << 10) + gr)) * 512 + (gcd >> 1)];
                    float cs = b2f((u16)(csn & 0xffff)), sn = b2f((u16)(csn >> 16));
                    float res = (gcd & 1) ? (cs * my - sn * other)
                                          : (cs * my + sn * other);
                    ((u16*)Dp)[o] = f2b(res);
                }
            }
        }
    }
}

// ---------------------------------------------------------------------------
// 256x256 NT GEMM, TWO phases per K-tile (32-MFMA clusters) — EXACT r5
// structure (best measured: QKV 126.7 us / ~814 TF). Used for QKV and proj.
// 8 waves (2M x 4N), BK=64, LDS 128 KiB (2 dbuf x (A 32K + B 32K)).
//
// Phase p = rq. rq=0: read 8 A-frags + 8 B-frags (reg-cached both k-halves);
// rq=1: read 8 A-frags, reuse cached B. lgkmcnt(0)+sched_barrier pin before
// the 32-MFMA cluster (r7 proved removing it regresses), setprio around MFMA,
// counted vmcnt at phase end, one s_barrier per phase.
// Ledger: ph0 issues next A0,A2,B0,B1; ph1 issues next B2,B3,A1,A3.
// ph0-end vmcnt(4); ph1-end vmcnt(2); tails vmcnt(0)/lgkm only.
// LDS swizzle: k-chunk kc at physical kc ^ ((row>>1)&7) via inverse-swizzled
// global source (GLL dest linear); reads apply the same XOR. 0 conflicts.
//
// MODE 0: row x col grid, XCD-swizzled by row tile. EPI 0: +bias+rotate ->
// bf16 (k/q/vT split, v transposed); EPI 3: +bias -> f32.
// ---------------------------------------------------------------------------
template <int EPI, int MODE>
__global__ __launch_bounds__(512, 2) void gemm256(
    const u16* __restrict__ A, long long sAz,
    const u16* __restrict__ B, long long sBz,
    void* __restrict__ D0, void* __restrict__ D1, void* __restrict__ D2,
    long long sDz,
    const float* __restrict__ bias0, const float* __restrict__ bias1,
    const float* __restrict__ bias2,
    const u32* __restrict__ cossin,
    int N, int K, float scale, int WB)
{
    extern __shared__ u16 lds[];
    u16* const As = lds;                    // [2][4 chunks][64 rows][64]
    u16* const Bs = lds + 2 * 256 * 64;

    int bx, by, bz;
    {
        const int n = blockIdx.x;
        const int xcd = n & 7, m = n >> 3;
        by = xcd + 8 * (m / WB);
        bx = m % WB;
        bz = 0;
    }
    const int r0 = by * 256, c0 = bx * 256;

    const int nkt = K >> 6;

    const int tid = threadIdx.x;
    const int lane = tid & 63, wave = tid >> 6;
    const int wr = wave >> 2, wc = wave & 3;

    const u16* __restrict__ Ab = A + (long long)bz * sAz + (long long)r0 * K;
    const u16* __restrict__ Bb = B + (long long)bz * sBz + (long long)c0 * K;

    const int srow = tid >> 3;
    const int skc8 = (((tid & 7) ^ ((tid >> 4) & 7))) * 8;

    const int lr = lane & 15;
    const int xr = (lane >> 1) & 7;
    const int kof0 = (((lane >> 4) + 0) ^ xr) * 8;   // k-half 0
    const int kof1 = (((lane >> 4) + 4) ^ xr) * 8;   // k-half 1

    f32x4 acc[8][4];
    #pragma unroll
    for (int i = 0; i < 8; ++i)
        #pragma unroll
        for (int j = 0; j < 4; ++j)
            acc[i][j] = (f32x4){0.f, 0.f, 0.f, 0.f};

    // prologue: tile0's 8 lines, A1,A3 last; leave A1,A3 in flight
    #pragma unroll
    for (int r = 0; r < 4; ++r)
        GLL16(Bb + (long long)(r * 64 + srow) * K + skc8, Bs + r * 4096 + tid * 8);
    GLL16(Ab + (long long)(0 * 64 + srow) * K + skc8, As + 0 * 4096 + tid * 8);
    GLL16(Ab + (long long)(2 * 64 + srow) * K + skc8, As + 2 * 4096 + tid * 8);
    GLL16(Ab + (long long)(1 * 64 + srow) * K + skc8, As + 1 * 4096 + tid * 8);
    GLL16(Ab + (long long)(3 * 64 + srow) * K + skc8, As + 3 * 4096 + tid * 8);
    asm volatile("s_waitcnt vmcnt(2)" ::: "memory");
    __builtin_amdgcn_s_barrier();

    for (int kt = 0; kt < nkt; ++kt) {
        const int buf = kt & 1;
        const u16* asb = As + buf * 16384;
        const u16* bsb = Bs + buf * 16384;
        u16* asn = As + (buf ^ 1) * 16384;
        u16* bsn = Bs + (buf ^ 1) * 16384;
        const long long kbn = (long long)(kt + 1) * 64 + skc8;
        const bool pf = (kt + 1 < nkt);
        bf16x8 bc[2][4];                     // B frags cached across rq pair
        #pragma unroll
        for (int ph = 0; ph < 2; ++ph) {
            const int rq = ph;
            const int ab0 = wr * 128 + rq * 64;
            bf16x8 a0[4], a1[4];
            #pragma unroll
            for (int i = 0; i < 4; ++i) {
                const int row = (ab0 + i * 16 + lr) * 64;
                a0[i] = *(const bf16x8*)&asb[row + kof0];
                a1[i] = *(const bf16x8*)&asb[row + kof1];
            }
            if (rq == 0) {
                #pragma unroll
                for (int j = 0; j < 4; ++j) {
                    const int row = (wc * 64 + j * 16 + lr) * 64;
                    bc[0][j] = *(const bf16x8*)&bsb[row + kof0];
                    bc[1][j] = *(const bf16x8*)&bsb[row + kof1];
                }
            }
            if (pf) {
                if (ph == 0) {
                    GLL16(Ab + (long long)(0 * 64 + srow) * K + kbn, asn + 0 * 4096 + tid * 8);
                    GLL16(Ab + (long long)(2 * 64 + srow) * K + kbn, asn + 2 * 4096 + tid * 8);
                    GLL16(Bb + (long long)(0 * 64 + srow) * K + kbn, bsn + 0 * 4096 + tid * 8);
                    GLL16(Bb + (long long)(1 * 64 + srow) * K + kbn, bsn + 1 * 4096 + tid * 8);
                } else {
                    GLL16(Bb + (long long)(2 * 64 + srow) * K + kbn, bsn + 2 * 4096 + tid * 8);
                    GLL16(Bb + (long long)(3 * 64 + srow) * K + kbn, bsn + 3 * 4096 + tid * 8);
                    GLL16(Ab + (long long)(1 * 64 + srow) * K + kbn, asn + 1 * 4096 + tid * 8);
                    GLL16(Ab + (long long)(3 * 64 + srow) * K + kbn, asn + 3 * 4096 + tid * 8);
                }
            }
            asm volatile("s_waitcnt lgkmcnt(0)" ::: "memory");
            __builtin_amdgcn_sched_barrier(0);   // rule #18: pin MFMA after wait
            __builtin_amdgcn_s_setprio(1);
            #pragma unroll
            for (int i = 0; i < 4; ++i)
                #pragma unroll
                for (int j = 0; j < 4; ++j) {
                    acc[rq * 4 + i][j] = __builtin_amdgcn_mfma_f32_16x16x32_bf16(
                        a0[i], bc[0][j], acc[rq * 4 + i][j], 0, 0, 0);
                    acc[rq * 4 + i][j] = __builtin_amdgcn_mfma_f32_16x16x32_bf16(
                        a1[i], bc[1][j], acc[rq * 4 + i][j], 0, 0, 0);
                }
            __builtin_amdgcn_s_setprio(0);
            if (ph == 0) {
                if (pf) asm volatile("s_waitcnt vmcnt(4)" ::: "memory");
                else    asm volatile("s_waitcnt vmcnt(0)" ::: "memory");
            } else if (pf) {
                asm volatile("s_waitcnt vmcnt(2)" ::: "memory");
            }
            __builtin_amdgcn_s_barrier();
        }
    }

    // output routing (uniform per block)
    void* Dp = D0;
    const float* bp_ = bias0;
    int ldD = N, cbase = c0, sel = 0;
    if (EPI == 0) {
        sel = bx >> 2;                 // 4 tiles of 256 per 1024-col group
        Dp  = (sel == 0) ? D0 : (sel == 1) ? D1 : D2;
        bp_ = (sel == 0) ? bias0 : (sel == 1) ? bias1 : bias2;
        ldD = 1024;
        cbase = c0 & 1023;
    }

    // epilogue: C/D layout col=lane&15, row=(lane>>4)*4+reg
    const int rl = (lane >> 4) * 4, cl = lane & 15;
    const int grb = r0 + wr * 128;
    const int gcb = cbase + wc * 64;

    if (EPI == 0 && sel == 2) {
        // v group: bias + rotate + TRANSPOSED store into vT[b][c][t]
        #pragma unroll
        for (int ai = 0; ai < 8; ++ai) {
            #pragma unroll
            for (int bj = 0; bj < 4; ++bj) {
                const int gr0 = grb + ai * 16 + rl;       // 4-aligned t base
                const int gcd = gcb + bj * 16 + cl;       // v column
                u16 pk[4];
                #pragma unroll
                for (int v = 0; v < 4; ++v) {
                    const int gr = gr0 + v;
                    float my = acc[ai][bj][v] + bp_[gcd];
                    float other = __shfl_xor(my, 1);
                    u32 csn = cossin[(long long)gr * 512 + (gcd >> 1)];
                    float cs = b2f((u16)(csn & 0xffff)), sn = b2f((u16)(csn >> 16));
                    float res = (gcd & 1) ? (sn * other + cs * my)
                                          : (cs * my - sn * other);
                    pk[v] = f2b(res);
                }
                const int bb = gr0 >> 10, tt = gr0 & 1023;
                u16* dst = (u16*)Dp + ((((long long)bb << 10) + gcd) << 10) + tt;
                uint2 pw;
                pw.x = (u32)pk[0] | ((u32)pk[1] << 16);
                pw.y = (u32)pk[2] | ((u32)pk[3] << 16);
                *(uint2*)dst = pw;
            }
        }
        return;
    }

    #pragma unroll
    for (int ai = 0; ai < 8; ++ai) {
        #pragma unroll
        for (int bj = 0; bj < 4; ++bj) {
            const int gr0 = grb + ai * 16 + rl;
            const int gcd = gcb + bj * 16 + cl;
            #pragma unroll
            for (int v = 0; v < 4; ++v) {
                const int gr = gr0 + v;
                float val = acc[ai][bj][v];
                const long long o = (long long)gr * ldD + gcd;
                if (EPI == 0) {
                    float my = val + bp_[gcd];
                    float other = __shfl_xor(my, 1);
                    u32 csn = cossin[(long long)gr * 512 + (gcd >> 1)];
                    float cs = b2f((u16)(csn & 0xffff)), sn = b2f((u16)(csn >> 16));
                    float res = (gcd & 1) ? (sn * other + cs * my)
                                          : (cs * my - sn * other);
                    ((u16*)Dp)[o] = f2b(res);
                } else {
                    ((float*)Dp)[o] = val + bp_[gcd];
                }
            }
        }
    }
}

// ---------------------------------------------------------------------------
// Merged prep: x->bf16 (16384 blocks) | 4 weights->bf16 (4096) |
// angle partial sums (1024). One dispatch instead of three.
// ---------------------------------------------------------------------------
#define TT 1024
#define CC2 512
#define NCH 32
#define CL 32

__global__ void prep(const float* __restrict__ x,
                     const float* __restrict__ Wk, const float* __restrict__ Wq,
                     const float* __restrict__ Wv, const float* __restrict__ Wp,
                     u16* __restrict__ xb, u16* __restrict__ wall,
                     u16* __restrict__ wpb,
                     const int* __restrict__ idx, const float* __restrict__ emb,
                     float* __restrict__ partial)
{
    const int bid = blockIdx.x, tid = threadIdx.x;
    if (bid < 16384) {                       // x -> bf16 (float4/thread)
        const int i = bid * 256 + tid;
        float4 f = ((const float4*)x)[i];
        uint2 o;
        o.x = (u32)f2b(f.x) | ((u32)f2b(f.y) << 16);
        o.y = (u32)f2b(f.z) | ((u32)f2b(f.w) << 16);
        ((uint2*)xb)[i] = o;
    } else if (bid < 20480) {                // weights -> bf16
        const int s = bid - 16384;
        const int w = s >> 10;               // 0..3
        const int i = (s & 1023) * 256 + tid;
        const float* src = (w == 0) ? Wk : (w == 1) ? Wq : (w == 2) ? Wv : Wp;
        u16* dst = (w == 0) ? wall : (w == 1) ? wall + 1024 * 1024
                 : (w == 2) ? wall + 2 * 1024 * 1024 : wpb;
        float4 f = ((const float4*)src)[i];
        uint2 o;
        o.x = (u32)f2b(f.x) | ((u32)f2b(f.y) << 16);
        o.y = (u32)f2b(f.z) | ((u32)f2b(f.w) << 16);
        ((uint2*)dst)[i] = o;
    } else {                                 // angle partial sums
        const int s = bid - 20480;           // 0..1023
        const int b = s >> 6;
        const int r = s & 63;
        const int ch = r >> 1, half = r & 1;
        const int c = half * 256 + tid;      // 0..511
        float acc = 0.f;
        const int tb = ch * CL;
        for (int t = 0; t < CL; t++) {
            const int row = idx[b * TT + tb + t];
            acc += emb[(long long)row * CC2 + c];
        }
        partial[((long long)b * NCH + ch) * CC2 + c] = acc;
    }
}

__global__ void angle_final(const int* __restrict__ idx, const float* __restrict__ emb,
                            const float* __restrict__ partial,
                            u32* __restrict__ cossin) {
    int b = blockIdx.x >> 5, ch = blockIdx.x & 31;
    int c = threadIdx.x;
    // exclusive suffix over chunks after ch (same accumulation order as the
    // old serial scan: descending cc)
    float run = 0.f;
    for (int cc = NCH - 1; cc > ch; cc--)
        run += partial[((long long)b * NCH + cc) * CC2 + c];
    for (int t = CL - 1; t >= 0; t--) {
        int tt = ch * CL + t;
        int row = idx[b * TT + tt];
        run += emb[(long long)row * CC2 + c];
        float sn, cs;
        __sincosf(run, &sn, &cs);
        cossin[((long long)b * TT + tt) * CC2 + c] = (u32)f2b(cs) | ((u32)f2b(sn) << 16);
    }
}

// ---------------------------------------------------------------------------
extern "C" void kernel_launch(void* const* d_in, const int* in_sizes, int n_in,
                              void* d_out, int out_size, void* d_ws, size_t ws_size,
                              hipStream_t stream) {
    const int Bn = 16, T = 1024, C = 1024;
    const long long TC = (long long)T * C;
    const size_t nx = (size_t)Bn * T * C;          // 16,777,216
    const size_t npairs = nx / 2;                  // 8,388,608

    const float* x   = (const float*)d_in[0];
    const int*   idx = (const int*)d_in[1];
    const float* Wk  = (const float*)d_in[2];
    const float* bk  = (const float*)d_in[3];
    const float* Wq  = (const float*)d_in[4];
    const float* bq  = (const float*)d_in[5];
    const float* Wv  = (const float*)d_in[6];
    const float* bv  = (const float*)d_in[7];
    const float* Wp  = (const float*)d_in[8];
    const float* bp  = (const float*)d_in[9];
    const float* emb = (const float*)d_in[10];
    float* out = (float*)d_out;

    // one-time: allow 128 KiB dynamic LDS on the 256^2 kernels
    static bool s_attr = false;
    if (!s_attr) {
        auto* k0 = gemm256<0, 0>;
        auto* k3 = gemm256<3, 0>;
        (void)hipFuncSetAttribute(reinterpret_cast<const void*>(k0),
                                  hipFuncAttributeMaxDynamicSharedMemorySize, 131072);
        (void)hipFuncSetAttribute(reinterpret_cast<const void*>(k3),
                                  hipFuncAttributeMaxDynamicSharedMemorySize, 131072);
        s_attr = true;
    }

    // workspace (~171 MB)
    u16* xb  = (u16*)d_ws;          // x bf16; aliased as wei after QKV
    u16* kb  = xb + nx;             // k (rotated by QKV epilogue)
    u16* qb  = kb + nx;             // q (rotated); y after attn GEMM
    u16* vT  = qb + nx;             // v rotated+transposed [B][C][T]
    u32* cossin = (u32*)(vT + nx);  // [B][T][512] packed bf16 {cos,sin}
    u16* Wall = (u16*)(cossin + npairs);           // [3072][1024] = Wk|Wq|Wv
    u16* Wpb  = Wall + (size_t)3 * C * C;
    float* partial = (float*)(Wpb + (size_t)C * C);  // [B][32][512]
    u16* wei = xb;                  // alias (x dead after QKV)

    // 1) merged prep: conversions + angle partial sums (one dispatch)
    prep<<<21504, 256, 0, stream>>>(x, Wk, Wq, Wv, Wp, xb, Wall, Wpb,
                                    idx, emb, partial);

    // 2) angle suffix -> packed cos/sin
    angle_final<<<Bn * NCH, 512, 0, stream>>>(idx, emb, partial, cossin);

    // 3) fused QKV projection: M=16384, N=3072, K=1024; 64x12 tiles (256^2).
    gemm256<0, 0><<<768, 512, 131072, stream>>>(
        xb, 0, Wall, 0, kb, qb, vT, 0, bk, bq, bv, cossin,
        3 * C, C, 1.f, 12);

    // 4) wei = softplus(k @ q^T / 32), causal-masked; 128^2 kernel,
    //    batch-grouped swizzle, EARLY tril skip (3 resident blocks/CU)
    gemm_nt<1, true, false, 1, false><<<1024, 256, 0, stream>>>(
        kb, TC, qb, TC, wei, nullptr, nullptr, (long long)T * T,
        nullptr, nullptr, nullptr, nullptr, T, T, C, 0.03125f, 64);

    // 5) attn = wei @ v, inverse-rotation epilogue -> y (qb); 128^2 kernel,
    //    K truncated at causal boundary
    gemm_nt<2, false, true, 1, false><<<1024, 256, 0, stream>>>(
        wei, (long long)T * T, vT, (long long)C * T, qb, nullptr, nullptr, TC,
        nullptr, nullptr, nullptr, cossin, T, C, T, 1.f, 64);

    // 6) final projection -> f32 out: 64x4 tiles (256^2).
    gemm256<3, 0><<<256, 512, 131072, stream>>>(
        qb, 0, Wpb, 0, out, nullptr, nullptr, 0, bp, nullptr, nullptr, nullptr,
        C, C, 1.f, 4);
}

// Round 10
// 426.891 us; speedup vs baseline: 1.3850x; 1.0027x over previous
//
#include <hip/hip_runtime.h>
#include <math.h>

typedef unsigned short u16;
typedef unsigned int u32;
typedef __bf16 bf16x8 __attribute__((ext_vector_type(8)));
typedef float f32x4 __attribute__((ext_vector_type(4)));

#define BM 128
#define BN 128
#define BK 32

__device__ __forceinline__ u16 f2b(float f) {
    u32 u = __float_as_uint(f);
    return (u16)((u + 0x7FFFu + ((u >> 16) & 1u)) >> 16);
}
__device__ __forceinline__ float b2f(u16 h) {
    return __uint_as_float(((u32)h) << 16);
}

// async global->LDS, 16B per lane. LDS dest is wave-uniform base + lane*16.
#define GLL16(gp, lp)                                                          \
    __builtin_amdgcn_global_load_lds(                                          \
        (__attribute__((address_space(1))) void*)(const_cast<u16*>(gp)),       \
        (__attribute__((address_space(3))) void*)(lp), 16, 0, 0)

// ---------------------------------------------------------------------------
// 128x128 m97-structure NT GEMM — used for wei / attn (small grids, short or
// tril K). 256 threads / 4 waves, VGPR ~100 -> ~3 resident blocks per CU:
// inter-block wave overlap (m114) hides the per-K-step barrier drain.
// EPI 1 = softplus(scale*x) causal-masked -> bf16 (fast __logf form)
// EPI 2 = inverse pair-rotate -> bf16
// KLIM: truncate K at causal boundary.
// SWZ=1: batch-grouped XCD swizzle (bz = XCD), full rectangular tile grid.
// SWZ=2: batch-grouped XCD swizzle, LOWER-TRIANGULAR tile enumeration
//        (36 live tiles of the 8x8 grid; no dead-block launches).
// ---------------------------------------------------------------------------
template <int EPI, bool EARLY, bool KLIM, int SWZ, bool SPLIT>
__global__ __launch_bounds__(256) void gemm_nt(
    const u16* __restrict__ A, long long sAz,
    const u16* __restrict__ B, long long sBz,
    void* __restrict__ D0, void* __restrict__ D1, void* __restrict__ D2,
    long long sDz,
    const float* __restrict__ bias0, const float* __restrict__ bias1,
    const float* __restrict__ bias2,
    const u32* __restrict__ cossin,
    int M, int N, int K, float scale, int WB)
{
    int bx, by, bz;
    {
        const int n = blockIdx.x;
        const int xcd = n & 7, m = n >> 3;
        if (SWZ == 1) {
            bz = xcd + 8 * (m / WB);
            const int w = m % WB;
            bx = w & 7;
            by = w >> 3;
        } else {
            // SWZ == 2: tril enumeration, 36 tiles/batch, 2 batches per XCD
            bz = xcd + 8 * (m / 36);
            const int t = m % 36;
            by = (t >= 1) + (t >= 3) + (t >= 6) + (t >= 10) + (t >= 15)
               + (t >= 21) + (t >= 28);
            bx = t - ((by * (by + 1)) >> 1);
        }
    }
    const int r0 = by * BM, c0 = bx * BN;

    if (EARLY && c0 >= r0 + BM) return;   // fully masked tile; never read later

    __shared__ __align__(16) u16 As[BM * BK];
    __shared__ __align__(16) u16 Bs[BN * BK];

    const int tid = threadIdx.x;
    const int lane = tid & 63, wave = tid >> 6;
    const int wm = (wave >> 1) * 64, wn = (wave & 1) * 64;

    const u16* Ab = A + (long long)bz * sAz + (long long)r0 * K;
    const u16* Bb = B + (long long)bz * sBz + (long long)c0 * K;

    const int ra0 = tid >> 2;          // row 0..63 (second issue: +64)
    const int ca0 = (tid & 3) * 8;     // k-chunk within row

    f32x4 acc[4][4];
    #pragma unroll
    for (int i = 0; i < 4; i++)
        #pragma unroll
        for (int j = 0; j < 4; j++)
            acc[i][j] = (f32x4){0.f, 0.f, 0.f, 0.f};

    const int kEnd = KLIM ? ((r0 + BM) < K ? (r0 + BM) : K) : K;

    for (int k0 = 0; k0 < kEnd; k0 += BK) {
        GLL16(Ab + (long long)ra0 * K + k0 + ca0,        &As[tid * 8]);
        GLL16(Ab + (long long)(ra0 + 64) * K + k0 + ca0, &As[(tid + 256) * 8]);
        GLL16(Bb + (long long)ra0 * K + k0 + ca0,        &Bs[tid * 8]);
        GLL16(Bb + (long long)(ra0 + 64) * K + k0 + ca0, &Bs[(tid + 256) * 8]);
        __syncthreads();

        bf16x8 af[4], bfv[4];
        #pragma unroll
        for (int i = 0; i < 4; i++) {
            af[i]  = *(const bf16x8*)&As[(wm + i * 16 + (lane & 15)) * BK + (lane >> 4) * 8];
            bfv[i] = *(const bf16x8*)&Bs[(wn + i * 16 + (lane & 15)) * BK + (lane >> 4) * 8];
        }
        #pragma unroll
        for (int i = 0; i < 4; i++)
            #pragma unroll
            for (int j = 0; j < 4; j++)
                acc[i][j] = __builtin_amdgcn_mfma_f32_16x16x32_bf16(af[i], bfv[j], acc[i][j], 0, 0, 0);
        __syncthreads();
    }

    void* Dp = D0;
    int ldD = N;
    const int cbase = c0;

    // epilogue: C/D layout col=lane&15, row=(lane>>4)*4+reg
    const int rl = (lane >> 4) * 4, cl = lane & 15;

    #pragma unroll
    for (int i = 0; i < 4; i++) {
        #pragma unroll
        for (int j = 0; j < 4; j++) {
            const int gr0 = r0 + wm + i * 16 + rl;
            const int gc  = wn + j * 16 + cl;
            const int gcd = cbase + gc;
            #pragma unroll
            for (int v = 0; v < 4; v++) {
                const int gr = gr0 + v;
                float val = acc[i][j][v];
                const long long o = (long long)bz * sDz + (long long)gr * ldD + gcd;
                if (EPI == 1) {
                    float xs = val * scale;
                    float r = (gcd <= gr) ? ((xs > 15.f) ? xs : __logf(1.f + __expf(xs))) : 0.f;
                    ((u16*)Dp)[o] = f2b(r);
                } else if (EPI == 2) {
                    float my = val;
                    float other = __shfl_xor(my, 1);
                    u32 csn = cossin[((long long)((bz << 10) + gr)) * 512 + (gcd >> 1)];
                    float cs = b2f((u16)(csn & 0xffff)), sn = b2f((u16)(csn >> 16));
                    float res = (gcd & 1) ? (cs * my - sn * other)
                                          : (cs * my + sn * other);
                    ((u16*)Dp)[o] = f2b(res);
                }
            }
        }
    }
}

// ---------------------------------------------------------------------------
// 256x256 NT GEMM, TWO phases per K-tile (32-MFMA clusters) — EXACT r5
// K-loop (best measured: QKV 126.7 us / ~814 TF). Used for QKV and proj.
// 8 waves (2M x 4N), BK=64, LDS 128 KiB (2 dbuf x (A 32K + B 32K)).
//
// r10: bx-MAJOR block ordering. Per XCD, the 8 concurrently-resident
// by-blocks (one per CU-group) now share the SAME bx (B-panel): one L3 pull
// serves 8 readers through L2, instead of each by-group sequentially
// re-pulling all 12 B-panels (6 MB > 4 MB L2). Each XCD's A-slice (8 fixed
// by-panels, 4 MB) is revisited for every bx -> stays L2/L3-hot across the
// dispatch. Delivery model: QKV is staging-delivery-bound at ~10 B/cyc/CU
// (fits both the 814 TF 256^2 and 523 TF 128^2 measurements); this ordering
// attacks the L3/HBM share of that delivery.
//
// Phase p = rq. rq=0: read 8 A-frags + 8 B-frags (reg-cached both k-halves);
// rq=1: read 8 A-frags, reuse cached B. lgkmcnt(0)+sched_barrier pin before
// the 32-MFMA cluster (r7 proved removing it regresses), setprio around MFMA,
// counted vmcnt at phase end, one s_barrier per phase.
// Ledger: ph0 issues next A0,A2,B0,B1; ph1 issues next B2,B3,A1,A3.
// ph0-end vmcnt(4); ph1-end vmcnt(2); tails vmcnt(0)/lgkm only.
// LDS swizzle: k-chunk kc at physical kc ^ ((row>>1)&7) via inverse-swizzled
// global source (GLL dest linear); reads apply the same XOR. 0 conflicts.
//
// EPI 0: +bias+rotate -> bf16 (k/q/vT split, v transposed); EPI 3: +bias->f32.
// ---------------------------------------------------------------------------
template <int EPI, int MODE>
__global__ __launch_bounds__(512, 2) void gemm256(
    const u16* __restrict__ A, long long sAz,
    const u16* __restrict__ B, long long sBz,
    void* __restrict__ D0, void* __restrict__ D1, void* __restrict__ D2,
    long long sDz,
    const float* __restrict__ bias0, const float* __restrict__ bias1,
    const float* __restrict__ bias2,
    const u32* __restrict__ cossin,
    int N, int K, float scale, int WB)
{
    extern __shared__ u16 lds[];
    u16* const As = lds;                    // [2][4 chunks][64 rows][64]
    u16* const Bs = lds + 2 * 256 * 64;

    int bx, by, bz;
    {
        const int n = blockIdx.x;
        const int xcd = n & 7, m = n >> 3;
        by = xcd + 8 * (m & 7);     // bx-major: 8 by-blocks concurrent per XCD
        bx = m >> 3;                //           all share one B-panel
        bz = 0;
    }
    const int r0 = by * 256, c0 = bx * 256;

    const int nkt = K >> 6;

    const int tid = threadIdx.x;
    const int lane = tid & 63, wave = tid >> 6;
    const int wr = wave >> 2, wc = wave & 3;

    const u16* __restrict__ Ab = A + (long long)bz * sAz + (long long)r0 * K;
    const u16* __restrict__ Bb = B + (long long)bz * sBz + (long long)c0 * K;

    const int srow = tid >> 3;
    const int skc8 = (((tid & 7) ^ ((tid >> 4) & 7))) * 8;

    const int lr = lane & 15;
    const int xr = (lane >> 1) & 7;
    const int kof0 = (((lane >> 4) + 0) ^ xr) * 8;   // k-half 0
    const int kof1 = (((lane >> 4) + 4) ^ xr) * 8;   // k-half 1

    f32x4 acc[8][4];
    #pragma unroll
    for (int i = 0; i < 8; ++i)
        #pragma unroll
        for (int j = 0; j < 4; ++j)
            acc[i][j] = (f32x4){0.f, 0.f, 0.f, 0.f};

    // prologue: tile0's 8 lines, A1,A3 last; leave A1,A3 in flight
    #pragma unroll
    for (int r = 0; r < 4; ++r)
        GLL16(Bb + (long long)(r * 64 + srow) * K + skc8, Bs + r * 4096 + tid * 8);
    GLL16(Ab + (long long)(0 * 64 + srow) * K + skc8, As + 0 * 4096 + tid * 8);
    GLL16(Ab + (long long)(2 * 64 + srow) * K + skc8, As + 2 * 4096 + tid * 8);
    GLL16(Ab + (long long)(1 * 64 + srow) * K + skc8, As + 1 * 4096 + tid * 8);
    GLL16(Ab + (long long)(3 * 64 + srow) * K + skc8, As + 3 * 4096 + tid * 8);
    asm volatile("s_waitcnt vmcnt(2)" ::: "memory");
    __builtin_amdgcn_s_barrier();

    for (int kt = 0; kt < nkt; ++kt) {
        const int buf = kt & 1;
        const u16* asb = As + buf * 16384;
        const u16* bsb = Bs + buf * 16384;
        u16* asn = As + (buf ^ 1) * 16384;
        u16* bsn = Bs + (buf ^ 1) * 16384;
        const long long kbn = (long long)(kt + 1) * 64 + skc8;
        const bool pf = (kt + 1 < nkt);
        bf16x8 bc[2][4];                     // B frags cached across rq pair
        #pragma unroll
        for (int ph = 0; ph < 2; ++ph) {
            const int rq = ph;
            const int ab0 = wr * 128 + rq * 64;
            bf16x8 a0[4], a1[4];
            #pragma unroll
            for (int i = 0; i < 4; ++i) {
                const int row = (ab0 + i * 16 + lr) * 64;
                a0[i] = *(const bf16x8*)&asb[row + kof0];
                a1[i] = *(const bf16x8*)&asb[row + kof1];
            }
            if (rq == 0) {
                #pragma unroll
                for (int j = 0; j < 4; ++j) {
                    const int row = (wc * 64 + j * 16 + lr) * 64;
                    bc[0][j] = *(const bf16x8*)&bsb[row + kof0];
                    bc[1][j] = *(const bf16x8*)&bsb[row + kof1];
                }
            }
            if (pf) {
                if (ph == 0) {
                    GLL16(Ab + (long long)(0 * 64 + srow) * K + kbn, asn + 0 * 4096 + tid * 8);
                    GLL16(Ab + (long long)(2 * 64 + srow) * K + kbn, asn + 2 * 4096 + tid * 8);
                    GLL16(Bb + (long long)(0 * 64 + srow) * K + kbn, bsn + 0 * 4096 + tid * 8);
                    GLL16(Bb + (long long)(1 * 64 + srow) * K + kbn, bsn + 1 * 4096 + tid * 8);
                } else {
                    GLL16(Bb + (long long)(2 * 64 + srow) * K + kbn, bsn + 2 * 4096 + tid * 8);
                    GLL16(Bb + (long long)(3 * 64 + srow) * K + kbn, bsn + 3 * 4096 + tid * 8);
                    GLL16(Ab + (long long)(1 * 64 + srow) * K + kbn, asn + 1 * 4096 + tid * 8);
                    GLL16(Ab + (long long)(3 * 64 + srow) * K + kbn, asn + 3 * 4096 + tid * 8);
                }
            }
            asm volatile("s_waitcnt lgkmcnt(0)" ::: "memory");
            __builtin_amdgcn_sched_barrier(0);   // rule #18: pin MFMA after wait
            __builtin_amdgcn_s_setprio(1);
            #pragma unroll
            for (int i = 0; i < 4; ++i)
                #pragma unroll
                for (int j = 0; j < 4; ++j) {
                    acc[rq * 4 + i][j] = __builtin_amdgcn_mfma_f32_16x16x32_bf16(
                        a0[i], bc[0][j], acc[rq * 4 + i][j], 0, 0, 0);
                    acc[rq * 4 + i][j] = __builtin_amdgcn_mfma_f32_16x16x32_bf16(
                        a1[i], bc[1][j], acc[rq * 4 + i][j], 0, 0, 0);
                }
            __builtin_amdgcn_s_setprio(0);
            if (ph == 0) {
                if (pf) asm volatile("s_waitcnt vmcnt(4)" ::: "memory");
                else    asm volatile("s_waitcnt vmcnt(0)" ::: "memory");
            } else if (pf) {
                asm volatile("s_waitcnt vmcnt(2)" ::: "memory");
            }
            __builtin_amdgcn_s_barrier();
        }
    }

    // output routing (uniform per block)
    void* Dp = D0;
    const float* bp_ = bias0;
    int ldD = N, cbase = c0, sel = 0;
    if (EPI == 0) {
        sel = bx >> 2;                 // 4 tiles of 256 per 1024-col group
        Dp  = (sel == 0) ? D0 : (sel == 1) ? D1 : D2;
        bp_ = (sel == 0) ? bias0 : (sel == 1) ? bias1 : bias2;
        ldD = 1024;
        cbase = c0 & 1023;
    }

    // epilogue: C/D layout col=lane&15, row=(lane>>4)*4+reg
    const int rl = (lane >> 4) * 4, cl = lane & 15;
    const int grb = r0 + wr * 128;
    const int gcb = cbase + wc * 64;

    if (EPI == 0 && sel == 2) {
        // v group: bias + rotate + TRANSPOSED store into vT[b][c][t]
        #pragma unroll
        for (int ai = 0; ai < 8; ++ai) {
            #pragma unroll
            for (int bj = 0; bj < 4; ++bj) {
                const int gr0 = grb + ai * 16 + rl;       // 4-aligned t base
                const int gcd = gcb + bj * 16 + cl;       // v column
                u16 pk[4];
                #pragma unroll
                for (int v = 0; v < 4; ++v) {
                    const int gr = gr0 + v;
                    float my = acc[ai][bj][v] + bp_[gcd];
                    float other = __shfl_xor(my, 1);
                    u32 csn = cossin[(long long)gr * 512 + (gcd >> 1)];
                    float cs = b2f((u16)(csn & 0xffff)), sn = b2f((u16)(csn >> 16));
                    float res = (gcd & 1) ? (sn * other + cs * my)
                                          : (cs * my - sn * other);
                    pk[v] = f2b(res);
                }
                const int bb = gr0 >> 10, tt = gr0 & 1023;
                u16* dst = (u16*)Dp + ((((long long)bb << 10) + gcd) << 10) + tt;
                uint2 pw;
                pw.x = (u32)pk[0] | ((u32)pk[1] << 16);
                pw.y = (u32)pk[2] | ((u32)pk[3] << 16);
                *(uint2*)dst = pw;
            }
        }
        return;
    }

    #pragma unroll
    for (int ai = 0; ai < 8; ++ai) {
        #pragma unroll
        for (int bj = 0; bj < 4; ++bj) {
            const int gr0 = grb + ai * 16 + rl;
            const int gcd = gcb + bj * 16 + cl;
            #pragma unroll
            for (int v = 0; v < 4; ++v) {
                const int gr = gr0 + v;
                float val = acc[ai][bj][v];
                const long long o = (long long)gr * ldD + gcd;
                if (EPI == 0) {
                    float my = val + bp_[gcd];
                    float other = __shfl_xor(my, 1);
                    u32 csn = cossin[(long long)gr * 512 + (gcd >> 1)];
                    float cs = b2f((u16)(csn & 0xffff)), sn = b2f((u16)(csn >> 16));
                    float res = (gcd & 1) ? (sn * other + cs * my)
                                          : (cs * my - sn * other);
                    ((u16*)Dp)[o] = f2b(res);
                } else {
                    ((float*)Dp)[o] = val + bp_[gcd];
                }
            }
        }
    }
}

// ---------------------------------------------------------------------------
// Merged prep: x->bf16 (16384 blocks) | 4 weights->bf16 (4096) |
// angle partial sums (1024). One dispatch instead of three.
// ---------------------------------------------------------------------------
#define TT 1024
#define CC2 512
#define NCH 32
#define CL 32

__global__ void prep(const float* __restrict__ x,
                     const float* __restrict__ Wk, const float* __restrict__ Wq,
                     const float* __restrict__ Wv, const float* __restrict__ Wp,
                     u16* __restrict__ xb, u16* __restrict__ wall,
                     u16* __restrict__ wpb,
                     const int* __restrict__ idx, const float* __restrict__ emb,
                     float* __restrict__ partial)
{
    const int bid = blockIdx.x, tid = threadIdx.x;
    if (bid < 16384) {                       // x -> bf16 (float4/thread)
        const int i = bid * 256 + tid;
        float4 f = ((const float4*)x)[i];
        uint2 o;
        o.x = (u32)f2b(f.x) | ((u32)f2b(f.y) << 16);
        o.y = (u32)f2b(f.z) | ((u32)f2b(f.w) << 16);
        ((uint2*)xb)[i] = o;
    } else if (bid < 20480) {                // weights -> bf16
        const int s = bid - 16384;
        const int w = s >> 10;               // 0..3
        const int i = (s & 1023) * 256 + tid;
        const float* src = (w == 0) ? Wk : (w == 1) ? Wq : (w == 2) ? Wv : Wp;
        u16* dst = (w == 0) ? wall : (w == 1) ? wall + 1024 * 1024
                 : (w == 2) ? wall + 2 * 1024 * 1024 : wpb;
        float4 f = ((const float4*)src)[i];
        uint2 o;
        o.x = (u32)f2b(f.x) | ((u32)f2b(f.y) << 16);
        o.y = (u32)f2b(f.z) | ((u32)f2b(f.w) << 16);
        ((uint2*)dst)[i] = o;
    } else {                                 // angle partial sums
        const int s = bid - 20480;           // 0..1023
        const int b = s >> 6;
        const int r = s & 63;
        const int ch = r >> 1, half = r & 1;
        const int c = half * 256 + tid;      // 0..511
        float acc = 0.f;
        const int tb = ch * CL;
        for (int t = 0; t < CL; t++) {
            const int row = idx[b * TT + tb + t];
            acc += emb[(long long)row * CC2 + c];
        }
        partial[((long long)b * NCH + ch) * CC2 + c] = acc;
    }
}

__global__ void angle_final(const int* __restrict__ idx, const float* __restrict__ emb,
                            const float* __restrict__ partial,
                            u32* __restrict__ cossin) {
    int b = blockIdx.x >> 5, ch = blockIdx.x & 31;
    int c = threadIdx.x;
    // exclusive suffix over chunks after ch (same accumulation order as the
    // old serial scan: descending cc)
    float run = 0.f;
    for (int cc = NCH - 1; cc > ch; cc--)
        run += partial[((long long)b * NCH + cc) * CC2 + c];
    for (int t = CL - 1; t >= 0; t--) {
        int tt = ch * CL + t;
        int row = idx[b * TT + tt];
        run += emb[(long long)row * CC2 + c];
        float sn, cs;
        __sincosf(run, &sn, &cs);
        cossin[((long long)b * TT + tt) * CC2 + c] = (u32)f2b(cs) | ((u32)f2b(sn) << 16);
    }
}

// ---------------------------------------------------------------------------
extern "C" void kernel_launch(void* const* d_in, const int* in_sizes, int n_in,
                              void* d_out, int out_size, void* d_ws, size_t ws_size,
                              hipStream_t stream) {
    const int Bn = 16, T = 1024, C = 1024;
    const long long TC = (long long)T * C;
    const size_t nx = (size_t)Bn * T * C;          // 16,777,216
    const size_t npairs = nx / 2;                  // 8,388,608

    const float* x   = (const float*)d_in[0];
    const int*   idx = (const int*)d_in[1];
    const float* Wk  = (const float*)d_in[2];
    const float* bk  = (const float*)d_in[3];
    const float* Wq  = (const float*)d_in[4];
    const float* bq  = (const float*)d_in[5];
    const float* Wv  = (const float*)d_in[6];
    const float* bv  = (const float*)d_in[7];
    const float* Wp  = (const float*)d_in[8];
    const float* bp  = (const float*)d_in[9];
    const float* emb = (const float*)d_in[10];
    float* out = (float*)d_out;

    // one-time: allow 128 KiB dynamic LDS on the 256^2 kernels
    static bool s_attr = false;
    if (!s_attr) {
        auto* k0 = gemm256<0, 0>;
        auto* k3 = gemm256<3, 0>;
        (void)hipFuncSetAttribute(reinterpret_cast<const void*>(k0),
                                  hipFuncAttributeMaxDynamicSharedMemorySize, 131072);
        (void)hipFuncSetAttribute(reinterpret_cast<const void*>(k3),
                                  hipFuncAttributeMaxDynamicSharedMemorySize, 131072);
        s_attr = true;
    }

    // workspace (~171 MB)
    u16* xb  = (u16*)d_ws;          // x bf16; aliased as wei after QKV
    u16* kb  = xb + nx;             // k (rotated by QKV epilogue)
    u16* qb  = kb + nx;             // q (rotated); y after attn GEMM
    u16* vT  = qb + nx;             // v rotated+transposed [B][C][T]
    u32* cossin = (u32*)(vT + nx);  // [B][T][512] packed bf16 {cos,sin}
    u16* Wall = (u16*)(cossin + npairs);           // [3072][1024] = Wk|Wq|Wv
    u16* Wpb  = Wall + (size_t)3 * C * C;
    float* partial = (float*)(Wpb + (size_t)C * C);  // [B][32][512]
    u16* wei = xb;                  // alias (x dead after QKV)

    // 1) merged prep: conversions + angle partial sums (one dispatch)
    prep<<<21504, 256, 0, stream>>>(x, Wk, Wq, Wv, Wp, xb, Wall, Wpb,
                                    idx, emb, partial);

    // 2) angle suffix -> packed cos/sin
    angle_final<<<Bn * NCH, 512, 0, stream>>>(idx, emb, partial, cossin);

    // 3) fused QKV projection: M=16384, N=3072, K=1024; 64x12 tiles (256^2),
    //    bx-major per-XCD ordering (B-panel shared by 8 concurrent blocks).
    gemm256<0, 0><<<768, 512, 131072, stream>>>(
        xb, 0, Wall, 0, kb, qb, vT, 0, bk, bq, bv, cossin,
        3 * C, C, 1.f, 12);

    // 4) wei = softplus(k @ q^T / 32), causal; 128^2 kernel, tril-enumerated
    //    grid (576 live tiles, no dead launches), batch-grouped XCD swizzle
    gemm_nt<1, false, false, 2, false><<<576, 256, 0, stream>>>(
        kb, TC, qb, TC, wei, nullptr, nullptr, (long long)T * T,
        nullptr, nullptr, nullptr, nullptr, T, T, C, 0.03125f, 0);

    // 5) attn = wei @ v, inverse-rotation epilogue -> y (qb); 128^2 kernel,
    //    K truncated at causal boundary
    gemm_nt<2, false, true, 1, false><<<1024, 256, 0, stream>>>(
        wei, (long long)T * T, vT, (long long)C * T, qb, nullptr, nullptr, TC,
        nullptr, nullptr, nullptr, cossin, T, C, T, 1.f, 64);

    // 6) final projection -> f32 out: 64x4 tiles (256^2), bx-major ordering.
    gemm256<3, 0><<<256, 512, 131072, stream>>>(
        qb, 0, Wpb, 0, out, nullptr, nullptr, 0, bp, nullptr, nullptr, nullptr,
        C, C, 1.f, 4);
}

// Round 12
// 423.056 us; speedup vs baseline: 1.3975x; 1.0091x over previous
//
#include <hip/hip_runtime.h>
#include <math.h>

typedef unsigned short u16;
typedef unsigned int u32;
typedef __bf16 bf16x8 __attribute__((ext_vector_type(8)));
typedef float f32x4 __attribute__((ext_vector_type(4)));

#define BM 128
#define BN 128
#define BK 32

__device__ __forceinline__ u16 f2b(float f) {
    u32 u = __float_as_uint(f);
    return (u16)((u + 0x7FFFu + ((u >> 16) & 1u)) >> 16);
}
__device__ __forceinline__ float b2f(u16 h) {
    return __uint_as_float(((u32)h) << 16);
}

// async global->LDS, 16B per lane. LDS dest is wave-uniform base + lane*16.
#define GLL16(gp, lp)                                                          \
    __builtin_amdgcn_global_load_lds(                                          \
        (__attribute__((address_space(1))) void*)(const_cast<u16*>(gp)),       \
        (__attribute__((address_space(3))) void*)(lp), 16, 0, 0)

// ---------------------------------------------------------------------------
// 128x128 m97-structure NT GEMM — used for wei / attn (small grids, short or
// tril K). 256 threads / 4 waves, VGPR ~100 -> ~3 resident blocks per CU:
// inter-block wave overlap (m114) hides the per-K-step barrier drain.
// EPI 1 = softplus(scale*x) causal-masked -> bf16 (fast __logf form)
// EPI 2 = inverse pair-rotate -> bf16
// KLIM: truncate K at causal boundary.
// SWZ=1: batch-grouped XCD swizzle, by DESCENDING (longest-first for KLIM:
//        1024-K blocks scheduled first, short blocks pack the tail — LPT).
// SWZ=2: batch-grouped XCD swizzle, LOWER-TRIANGULAR tile enumeration
//        (36 live tiles of the 8x8 grid; no dead-block launches).
// ---------------------------------------------------------------------------
template <int EPI, bool EARLY, bool KLIM, int SWZ, bool SPLIT>
__global__ __launch_bounds__(256) void gemm_nt(
    const u16* __restrict__ A, long long sAz,
    const u16* __restrict__ B, long long sBz,
    void* __restrict__ D0, void* __restrict__ D1, void* __restrict__ D2,
    long long sDz,
    const float* __restrict__ bias0, const float* __restrict__ bias1,
    const float* __restrict__ bias2,
    const u32* __restrict__ cossin,
    int M, int N, int K, float scale, int WB)
{
    int bx, by, bz;
    {
        const int n = blockIdx.x;
        const int xcd = n & 7, m = n >> 3;
        if (SWZ == 1) {
            bz = xcd + 8 * (m / WB);
            const int w = m % WB;
            bx = w & 7;
            by = 7 - (w >> 3);          // descending: longest KLIM blocks first
        } else {
            // SWZ == 2: tril enumeration, 36 tiles/batch, 2 batches per XCD
            bz = xcd + 8 * (m / 36);
            const int t = m % 36;
            by = (t >= 1) + (t >= 3) + (t >= 6) + (t >= 10) + (t >= 15)
               + (t >= 21) + (t >= 28);
            bx = t - ((by * (by + 1)) >> 1);
        }
    }
    const int r0 = by * BM, c0 = bx * BN;

    if (EARLY && c0 >= r0 + BM) return;   // fully masked tile; never read later

    __shared__ __align__(16) u16 As[BM * BK];
    __shared__ __align__(16) u16 Bs[BN * BK];

    const int tid = threadIdx.x;
    const int lane = tid & 63, wave = tid >> 6;
    const int wm = (wave >> 1) * 64, wn = (wave & 1) * 64;

    const u16* Ab = A + (long long)bz * sAz + (long long)r0 * K;
    const u16* Bb = B + (long long)bz * sBz + (long long)c0 * K;

    const int ra0 = tid >> 2;          // row 0..63 (second issue: +64)
    const int ca0 = (tid & 3) * 8;     // k-chunk within row

    f32x4 acc[4][4];
    #pragma unroll
    for (int i = 0; i < 4; i++)
        #pragma unroll
        for (int j = 0; j < 4; j++)
            acc[i][j] = (f32x4){0.f, 0.f, 0.f, 0.f};

    const int kEnd = KLIM ? ((r0 + BM) < K ? (r0 + BM) : K) : K;

    for (int k0 = 0; k0 < kEnd; k0 += BK) {
        GLL16(Ab + (long long)ra0 * K + k0 + ca0,        &As[tid * 8]);
        GLL16(Ab + (long long)(ra0 + 64) * K + k0 + ca0, &As[(tid + 256) * 8]);
        GLL16(Bb + (long long)ra0 * K + k0 + ca0,        &Bs[tid * 8]);
        GLL16(Bb + (long long)(ra0 + 64) * K + k0 + ca0, &Bs[(tid + 256) * 8]);
        __syncthreads();

        bf16x8 af[4], bfv[4];
        #pragma unroll
        for (int i = 0; i < 4; i++) {
            af[i]  = *(const bf16x8*)&As[(wm + i * 16 + (lane & 15)) * BK + (lane >> 4) * 8];
            bfv[i] = *(const bf16x8*)&Bs[(wn + i * 16 + (lane & 15)) * BK + (lane >> 4) * 8];
        }
        #pragma unroll
        for (int i = 0; i < 4; i++)
            #pragma unroll
            for (int j = 0; j < 4; j++)
                acc[i][j] = __builtin_amdgcn_mfma_f32_16x16x32_bf16(af[i], bfv[j], acc[i][j], 0, 0, 0);
        __syncthreads();
    }

    void* Dp = D0;
    int ldD = N;
    const int cbase = c0;

    // epilogue: C/D layout col=lane&15, row=(lane>>4)*4+reg
    const int rl = (lane >> 4) * 4, cl = lane & 15;

    #pragma unroll
    for (int i = 0; i < 4; i++) {
        #pragma unroll
        for (int j = 0; j < 4; j++) {
            const int gr0 = r0 + wm + i * 16 + rl;
            const int gc  = wn + j * 16 + cl;
            const int gcd = cbase + gc;
            #pragma unroll
            for (int v = 0; v < 4; v++) {
                const int gr = gr0 + v;
                float val = acc[i][j][v];
                const long long o = (long long)bz * sDz + (long long)gr * ldD + gcd;
                if (EPI == 1) {
                    float xs = val * scale;
                    float r = (gcd <= gr) ? ((xs > 15.f) ? xs : __logf(1.f + __expf(xs))) : 0.f;
                    ((u16*)Dp)[o] = f2b(r);
                } else if (EPI == 2) {
                    float my = val;
                    float other = __shfl_xor(my, 1);
                    u32 csn = cossin[((long long)((bz << 10) + gr)) * 512 + (gcd >> 1)];
                    float cs = b2f((u16)(csn & 0xffff)), sn = b2f((u16)(csn >> 16));
                    float res = (gcd & 1) ? (cs * my - sn * other)
                                          : (cs * my + sn * other);
                    ((u16*)Dp)[o] = f2b(res);
                }
            }
        }
    }
}

// ---------------------------------------------------------------------------
// 256x256 NT GEMM, TWO phases per K-tile (32-MFMA clusters) — EXACT r5/r9
// K-loop AND r9 by-major block mapping (measured best: QKV 126.9 us, FETCH
// 115 GB; r10's bx-major variant regressed to 133 us / 123 GB — reverted).
// 8 waves (2M x 4N), BK=64, LDS 128 KiB (2 dbuf x (A 32K + B 32K)).
//
// Phase p = rq. rq=0: read 8 A-frags + 8 B-frags (reg-cached both k-halves);
// rq=1: read 8 A-frags, reuse cached B. lgkmcnt(0)+sched_barrier pin before
// the 32-MFMA cluster (r7 proved removing it regresses), setprio around MFMA,
// counted vmcnt at phase end, one s_barrier per phase.
// Ledger: ph0 issues next A0,A2,B0,B1; ph1 issues next B2,B3,A1,A3.
// ph0-end vmcnt(4); ph1-end vmcnt(2); tails vmcnt(0)/lgkm only.
// LDS swizzle: k-chunk kc at physical kc ^ ((row>>1)&7) via inverse-swizzled
// global source (GLL dest linear); reads apply the same XOR. 0 conflicts.
//
// EPI 0: +bias+rotate -> bf16 (k/q/vT split, v transposed); EPI 3: +bias->f32.
// ---------------------------------------------------------------------------
template <int EPI, int MODE>
__global__ __launch_bounds__(512, 2) void gemm256(
    const u16* __restrict__ A, long long sAz,
    const u16* __restrict__ B, long long sBz,
    void* __restrict__ D0, void* __restrict__ D1, void* __restrict__ D2,
    long long sDz,
    const float* __restrict__ bias0, const float* __restrict__ bias1,
    const float* __restrict__ bias2,
    const u32* __restrict__ cossin,
    int N, int K, float scale, int WB)
{
    extern __shared__ u16 lds[];
    u16* const As = lds;                    // [2][4 chunks][64 rows][64]
    u16* const Bs = lds + 2 * 256 * 64;

    int bx, by, bz;
    {
        const int n = blockIdx.x;
        const int xcd = n & 7, m = n >> 3;
        by = xcd + 8 * (m / WB);    // r9 by-major mapping (measured best)
        bx = m % WB;
        bz = 0;
    }
    const int r0 = by * 256, c0 = bx * 256;

    const int nkt = K >> 6;

    const int tid = threadIdx.x;
    const int lane = tid & 63, wave = tid >> 6;
    const int wr = wave >> 2, wc = wave & 3;

    const u16* __restrict__ Ab = A + (long long)bz * sAz + (long long)r0 * K;
    const u16* __restrict__ Bb = B + (long long)bz * sBz + (long long)c0 * K;

    const int srow = tid >> 3;
    const int skc8 = (((tid & 7) ^ ((tid >> 4) & 7))) * 8;

    const int lr = lane & 15;
    const int xr = (lane >> 1) & 7;
    const int kof0 = (((lane >> 4) + 0) ^ xr) * 8;   // k-half 0
    const int kof1 = (((lane >> 4) + 4) ^ xr) * 8;   // k-half 1

    f32x4 acc[8][4];
    #pragma unroll
    for (int i = 0; i < 8; ++i)
        #pragma unroll
        for (int j = 0; j < 4; ++j)
            acc[i][j] = (f32x4){0.f, 0.f, 0.f, 0.f};

    // prologue: tile0's 8 lines, A1,A3 last; leave A1,A3 in flight
    #pragma unroll
    for (int r = 0; r < 4; ++r)
        GLL16(Bb + (long long)(r * 64 + srow) * K + skc8, Bs + r * 4096 + tid * 8);
    GLL16(Ab + (long long)(0 * 64 + srow) * K + skc8, As + 0 * 4096 + tid * 8);
    GLL16(Ab + (long long)(2 * 64 + srow) * K + skc8, As + 2 * 4096 + tid * 8);
    GLL16(Ab + (long long)(1 * 64 + srow) * K + skc8, As + 1 * 4096 + tid * 8);
    GLL16(Ab + (long long)(3 * 64 + srow) * K + skc8, As + 3 * 4096 + tid * 8);
    asm volatile("s_waitcnt vmcnt(2)" ::: "memory");
    __builtin_amdgcn_s_barrier();

    for (int kt = 0; kt < nkt; ++kt) {
        const int buf = kt & 1;
        const u16* asb = As + buf * 16384;
        const u16* bsb = Bs + buf * 16384;
        u16* asn = As + (buf ^ 1) * 16384;
        u16* bsn = Bs + (buf ^ 1) * 16384;
        const long long kbn = (long long)(kt + 1) * 64 + skc8;
        const bool pf = (kt + 1 < nkt);
        bf16x8 bc[2][4];                     // B frags cached across rq pair
        #pragma unroll
        for (int ph = 0; ph < 2; ++ph) {
            const int rq = ph;
            const int ab0 = wr * 128 + rq * 64;
            bf16x8 a0[4], a1[4];
            #pragma unroll
            for (int i = 0; i < 4; ++i) {
                const int row = (ab0 + i * 16 + lr) * 64;
                a0[i] = *(const bf16x8*)&asb[row + kof0];
                a1[i] = *(const bf16x8*)&asb[row + kof1];
            }
            if (rq == 0) {
                #pragma unroll
                for (int j = 0; j < 4; ++j) {
                    const int row = (wc * 64 + j * 16 + lr) * 64;
                    bc[0][j] = *(const bf16x8*)&bsb[row + kof0];
                    bc[1][j] = *(const bf16x8*)&bsb[row + kof1];
                }
            }
            if (pf) {
                if (ph == 0) {
                    GLL16(Ab + (long long)(0 * 64 + srow) * K + kbn, asn + 0 * 4096 + tid * 8);
                    GLL16(Ab + (long long)(2 * 64 + srow) * K + kbn, asn + 2 * 4096 + tid * 8);
                    GLL16(Bb + (long long)(0 * 64 + srow) * K + kbn, bsn + 0 * 4096 + tid * 8);
                    GLL16(Bb + (long long)(1 * 64 + srow) * K + kbn, bsn + 1 * 4096 + tid * 8);
                } else {
                    GLL16(Bb + (long long)(2 * 64 + srow) * K + kbn, bsn + 2 * 4096 + tid * 8);
                    GLL16(Bb + (long long)(3 * 64 + srow) * K + kbn, bsn + 3 * 4096 + tid * 8);
                    GLL16(Ab + (long long)(1 * 64 + srow) * K + kbn, asn + 1 * 4096 + tid * 8);
                    GLL16(Ab + (long long)(3 * 64 + srow) * K + kbn, asn + 3 * 4096 + tid * 8);
                }
            }
            asm volatile("s_waitcnt lgkmcnt(0)" ::: "memory");
            __builtin_amdgcn_sched_barrier(0);   // rule #18: pin MFMA after wait
            __builtin_amdgcn_s_setprio(1);
            #pragma unroll
            for (int i = 0; i < 4; ++i)
                #pragma unroll
                for (int j = 0; j < 4; ++j) {
                    acc[rq * 4 + i][j] = __builtin_amdgcn_mfma_f32_16x16x32_bf16(
                        a0[i], bc[0][j], acc[rq * 4 + i][j], 0, 0, 0);
                    acc[rq * 4 + i][j] = __builtin_amdgcn_mfma_f32_16x16x32_bf16(
                        a1[i], bc[1][j], acc[rq * 4 + i][j], 0, 0, 0);
                }
            __builtin_amdgcn_s_setprio(0);
            if (ph == 0) {
                if (pf) asm volatile("s_waitcnt vmcnt(4)" ::: "memory");
                else    asm volatile("s_waitcnt vmcnt(0)" ::: "memory");
            } else if (pf) {
                asm volatile("s_waitcnt vmcnt(2)" ::: "memory");
            }
            __builtin_amdgcn_s_barrier();
        }
    }

    // output routing (uniform per block)
    void* Dp = D0;
    const float* bp_ = bias0;
    int ldD = N, cbase = c0, sel = 0;
    if (EPI == 0) {
        sel = bx >> 2;                 // 4 tiles of 256 per 1024-col group
        Dp  = (sel == 0) ? D0 : (sel == 1) ? D1 : D2;
        bp_ = (sel == 0) ? bias0 : (sel == 1) ? bias1 : bias2;
        ldD = 1024;
        cbase = c0 & 1023;
    }

    // epilogue: C/D layout col=lane&15, row=(lane>>4)*4+reg
    const int rl = (lane >> 4) * 4, cl = lane & 15;
    const int grb = r0 + wr * 128;
    const int gcb = cbase + wc * 64;

    if (EPI == 0 && sel == 2) {
        // v group: bias + rotate + TRANSPOSED store into vT[b][c][t]
        #pragma unroll
        for (int ai = 0; ai < 8; ++ai) {
            #pragma unroll
            for (int bj = 0; bj < 4; ++bj) {
                const int gr0 = grb + ai * 16 + rl;       // 4-aligned t base
                const int gcd = gcb + bj * 16 + cl;       // v column
                u16 pk[4];
                #pragma unroll
                for (int v = 0; v < 4; ++v) {
                    const int gr = gr0 + v;
                    float my = acc[ai][bj][v] + bp_[gcd];
                    float other = __shfl_xor(my, 1);
                    u32 csn = cossin[(long long)gr * 512 + (gcd >> 1)];
                    float cs = b2f((u16)(csn & 0xffff)), sn = b2f((u16)(csn >> 16));
                    float res = (gcd & 1) ? (sn * other + cs * my)
                                          : (cs * my - sn * other);
                    pk[v] = f2b(res);
                }
                const int bb = gr0 >> 10, tt = gr0 & 1023;
                u16* dst = (u16*)Dp + ((((long long)bb << 10) + gcd) << 10) + tt;
                uint2 pw;
                pw.x = (u32)pk[0] | ((u32)pk[1] << 16);
                pw.y = (u32)pk[2] | ((u32)pk[3] << 16);
                *(uint2*)dst = pw;
            }
        }
        return;
    }

    #pragma unroll
    for (int ai = 0; ai < 8; ++ai) {
        #pragma unroll
        for (int bj = 0; bj < 4; ++bj) {
            const int gr0 = grb + ai * 16 + rl;
            const int gcd = gcb + bj * 16 + cl;
            #pragma unroll
            for (int v = 0; v < 4; ++v) {
                const int gr = gr0 + v;
                float val = acc[ai][bj][v];
                const long long o = (long long)gr * ldD + gcd;
                if (EPI == 0) {
                    float my = val + bp_[gcd];
                    float other = __shfl_xor(my, 1);
                    u32 csn = cossin[(long long)gr * 512 + (gcd >> 1)];
                    float cs = b2f((u16)(csn & 0xffff)), sn = b2f((u16)(csn >> 16));
                    float res = (gcd & 1) ? (sn * other + cs * my)
                                          : (cs * my - sn * other);
                    ((u16*)Dp)[o] = f2b(res);
                } else {
                    ((float*)Dp)[o] = val + bp_[gcd];
                }
            }
        }
    }
}

// ---------------------------------------------------------------------------
// Merged prep: x->bf16 (16384 blocks) | 4 weights->bf16 (4096) |
// angle partial sums (1024). One dispatch instead of three.
// ---------------------------------------------------------------------------
#define TT 1024
#define CC2 512
#define NCH 32
#define CL 32

__global__ void prep(const float* __restrict__ x,
                     const float* __restrict__ Wk, const float* __restrict__ Wq,
                     const float* __restrict__ Wv, const float* __restrict__ Wp,
                     u16* __restrict__ xb, u16* __restrict__ wall,
                     u16* __restrict__ wpb,
                     const int* __restrict__ idx, const float* __restrict__ emb,
                     float* __restrict__ partial)
{
    const int bid = blockIdx.x, tid = threadIdx.x;
    if (bid < 16384) {                       // x -> bf16 (float4/thread)
        const int i = bid * 256 + tid;
        float4 f = ((const float4*)x)[i];
        uint2 o;
        o.x = (u32)f2b(f.x) | ((u32)f2b(f.y) << 16);
        o.y = (u32)f2b(f.z) | ((u32)f2b(f.w) << 16);
        ((uint2*)xb)[i] = o;
    } else if (bid < 20480) {                // weights -> bf16
        const int s = bid - 16384;
        const int w = s >> 10;               // 0..3
        const int i = (s & 1023) * 256 + tid;
        const float* src = (w == 0) ? Wk : (w == 1) ? Wq : (w == 2) ? Wv : Wp;
        u16* dst = (w == 0) ? wall : (w == 1) ? wall + 1024 * 1024
                 : (w == 2) ? wall + 2 * 1024 * 1024 : wpb;
        float4 f = ((const float4*)src)[i];
        uint2 o;
        o.x = (u32)f2b(f.x) | ((u32)f2b(f.y) << 16);
        o.y = (u32)f2b(f.z) | ((u32)f2b(f.w) << 16);
        ((uint2*)dst)[i] = o;
    } else {                                 // angle partial sums
        const int s = bid - 20480;           // 0..1023
        const int b = s >> 6;
        const int r = s & 63;
        const int ch = r >> 1, half = r & 1;
        const int c = half * 256 + tid;      // 0..511
        float acc = 0.f;
        const int tb = ch * CL;
        for (int t = 0; t < CL; t++) {
            const int row = idx[b * TT + tb + t];
            acc += emb[(long long)row * CC2 + c];
        }
        partial[((long long)b * NCH + ch) * CC2 + c] = acc;
    }
}

__global__ void angle_final(const int* __restrict__ idx, const float* __restrict__ emb,
                            const float* __restrict__ partial,
                            u32* __restrict__ cossin) {
    int b = blockIdx.x >> 5, ch = blockIdx.x & 31;
    int c = threadIdx.x;
    // exclusive suffix over chunks after ch (same accumulation order as the
    // old serial scan: descending cc)
    float run = 0.f;
    for (int cc = NCH - 1; cc > ch; cc--)
        run += partial[((long long)b * NCH + cc) * CC2 + c];
    for (int t = CL - 1; t >= 0; t--) {
        int tt = ch * CL + t;
        int row = idx[b * TT + tt];
        run += emb[(long long)row * CC2 + c];
        float sn, cs;
        __sincosf(run, &sn, &cs);
        cossin[((long long)b * TT + tt) * CC2 + c] = (u32)f2b(cs) | ((u32)f2b(sn) << 16);
    }
}

// ---------------------------------------------------------------------------
extern "C" void kernel_launch(void* const* d_in, const int* in_sizes, int n_in,
                              void* d_out, int out_size, void* d_ws, size_t ws_size,
                              hipStream_t stream) {
    const int Bn = 16, T = 1024, C = 1024;
    const long long TC = (long long)T * C;
    const size_t nx = (size_t)Bn * T * C;          // 16,777,216
    const size_t npairs = nx / 2;                  // 8,388,608

    const float* x   = (const float*)d_in[0];
    const int*   idx = (const int*)d_in[1];
    const float* Wk  = (const float*)d_in[2];
    const float* bk  = (const float*)d_in[3];
    const float* Wq  = (const float*)d_in[4];
    const float* bq  = (const float*)d_in[5];
    const float* Wv  = (const float*)d_in[6];
    const float* bv  = (const float*)d_in[7];
    const float* Wp  = (const float*)d_in[8];
    const float* bp  = (const float*)d_in[9];
    const float* emb = (const float*)d_in[10];
    float* out = (float*)d_out;

    // one-time: allow 128 KiB dynamic LDS on the 256^2 kernels
    static bool s_attr = false;
    if (!s_attr) {
        auto* k0 = gemm256<0, 0>;
        auto* k3 = gemm256<3, 0>;
        (void)hipFuncSetAttribute(reinterpret_cast<const void*>(k0),
                                  hipFuncAttributeMaxDynamicSharedMemorySize, 131072);
        (void)hipFuncSetAttribute(reinterpret_cast<const void*>(k3),
                                  hipFuncAttributeMaxDynamicSharedMemorySize, 131072);
        s_attr = true;
    }

    // workspace (~171 MB)
    u16* xb  = (u16*)d_ws;          // x bf16; aliased as wei after QKV
    u16* kb  = xb + nx;             // k (rotated by QKV epilogue)
    u16* qb  = kb + nx;             // q (rotated); y after attn GEMM
    u16* vT  = qb + nx;             // v rotated+transposed [B][C][T]
    u32* cossin = (u32*)(vT + nx);  // [B][T][512] packed bf16 {cos,sin}
    u16* Wall = (u16*)(cossin + npairs);           // [3072][1024] = Wk|Wq|Wv
    u16* Wpb  = Wall + (size_t)3 * C * C;
    float* partial = (float*)(Wpb + (size_t)C * C);  // [B][32][512]
    u16* wei = xb;                  // alias (x dead after QKV)

    // 1) merged prep: conversions + angle partial sums (one dispatch)
    prep<<<21504, 256, 0, stream>>>(x, Wk, Wq, Wv, Wp, xb, Wall, Wpb,
                                    idx, emb, partial);

    // 2) angle suffix -> packed cos/sin
    angle_final<<<Bn * NCH, 512, 0, stream>>>(idx, emb, partial, cossin);

    // 3) fused QKV projection: M=16384, N=3072, K=1024; 64x12 tiles (256^2),
    //    r9 by-major ordering (measured best).
    gemm256<0, 0><<<768, 512, 131072, stream>>>(
        xb, 0, Wall, 0, kb, qb, vT, 0, bk, bq, bv, cossin,
        3 * C, C, 1.f, 12);

    // 4) wei = softplus(k @ q^T / 32), causal; 128^2 kernel, tril-enumerated
    //    grid (576 live tiles, no dead launches), batch-grouped XCD swizzle
    gemm_nt<1, false, false, 2, false><<<576, 256, 0, stream>>>(
        kb, TC, qb, TC, wei, nullptr, nullptr, (long long)T * T,
        nullptr, nullptr, nullptr, nullptr, T, T, C, 0.03125f, 0);

    // 5) attn = wei @ v, inverse-rotation epilogue -> y (qb); 128^2 kernel,
    //    K truncated at causal boundary; by-descending (longest-first).
    gemm_nt<2, false, true, 1, false><<<1024, 256, 0, stream>>>(
        wei, (long long)T * T, vT, (long long)C * T, qb, nullptr, nullptr, TC,
        nullptr, nullptr, nullptr, cossin, T, C, T, 1.f, 64);

    // 6) final projection -> f32 out: 64x4 tiles (256^2), by-major ordering.
    gemm256<3, 0><<<256, 512, 131072, stream>>>(
        qb, 0, Wpb, 0, out, nullptr, nullptr, 0, bp, nullptr, nullptr, nullptr,
        C, C, 1.f, 4);
}